// Round 7
// baseline (155.072 us; speedup 1.0000x reference)
//
#include <hip/hip_runtime.h>
#include <hip/hip_bf16.h>
#include <math.h>

// Problem constants (from setup_inputs):
#define NN 1024
#define TT 128
#define SS 6
#define FF 2
#define HH 256
#define AA 18
#define MM 512
#define KH 20
#define BB (NN*SS)        // 6144
#define RR (FF*BB)        // 12288

#define SCL_RZ (-1.44269504089f)      // -log2(e): sigmoid(x)=rcp(1+exp2(-x*log2e))
#define SCL_N  (-2.88539008178f)      // -2*log2(e): tanh(x)=2*rcp(1+exp2(-2x*log2e))-1

typedef __bf16 bf16x8 __attribute__((ext_vector_type(8)));
typedef float f32x4 __attribute__((ext_vector_type(4)));
typedef unsigned ux4 __attribute__((ext_vector_type(4)));

__device__ __forceinline__ f32x4 mfma16(bf16x8 a, bf16x8 b, f32x4 c) {
    return __builtin_amdgcn_mfma_f32_16x16x32_bf16(a, b, c, 0, 0, 0);
}
__device__ __forceinline__ unsigned short f2b(float f) {
    return __builtin_bit_cast(unsigned short, __float2bfloat16(f));
}
__device__ __forceinline__ float b2f(unsigned short u) {
    return __builtin_bit_cast(float, (unsigned)u << 16);
}
__device__ __forceinline__ float rcp_f(float x)  { return __builtin_amdgcn_rcpf(x); }
__device__ __forceinline__ float exp2_f(float x) { return __builtin_amdgcn_exp2f(x); }

// ---- ws layout (bytes) ----
#define OFF_ACT   0UL                 // KH*BB int (act_t[ki][b]) = 491,520
#define OFF_HPRED 491520UL            // RR*HH bf16 = 6,291,456
#define OFF_WHH   6782976UL           // 768*256 bf16 (pre-scaled) = 393,216
#define OFF_W1T   7176192UL           // 512*256 bf16 = 262,144
#define OFF_W2T   7438336UL           // 512*512 bf16 = 524,288
#define OFF_W3T   7962624UL           // 256*512 bf16 = 262,144
#define OFF_WIHP  8224768UL           // 768*32 bf16 (pre-scaled, bias col 18) = 49,152
#define OFF_PART  8273920UL           // 256*3 f32 = 3,072

// Prep: scaled bf16 W_hh, transposed MLP weights, scaled wih_pad, action table.
__global__ void k_prep(const float* __restrict__ Whh, const float* __restrict__ W1,
                       const float* __restrict__ W2, const float* __restrict__ W3,
                       const float* __restrict__ Wih, const float* __restrict__ bih,
                       const float* __restrict__ bhh,
                       const int* __restrict__ actions, const int* __restrict__ ts,
                       unsigned short* whh_s, unsigned short* w1t, unsigned short* w2t,
                       unsigned short* w3t, unsigned short* wihp, int* act_t) {
    int idx = blockIdx.x * 256 + threadIdx.x;
    if (idx < 196608) {   // W_hh, pre-scaled per gate
        int wrow = idx >> 8;
        float scl = (wrow < 512) ? SCL_RZ : SCL_N;
        whh_s[idx] = f2b(Whh[idx] * scl);
        return;
    }
    idx -= 196608;
    if (idx < 131072) { int m = idx >> 8, k = idx & 255; w1t[idx] = f2b(W1[k * MM + m]); return; }
    idx -= 131072;
    if (idx < 262144) { int m = idx >> 9, k = idx & 511; w2t[idx] = f2b(W2[k * MM + m]); return; }
    idx -= 262144;
    if (idx < 131072) { int c = idx >> 9, k = idx & 511; w3t[idx] = f2b(W3[k * HH + c]); return; }
    idx -= 131072;
    if (idx < 24576) {   // wih_pad[c][k]: k<18 scaled Wih; k==18 scaled biases; else 0
        int c = idx >> 5, k = idx & 31;
        int g = c >> 8;
        float scl = (g < 2) ? SCL_RZ : SCL_N;
        float v = 0.f;
        if (k < AA) v = scl * Wih[c * AA + k];
        else if (k == AA) v = scl * (bih[c] + ((g < 2) ? bhh[c] : 0.f));
        wihp[idx] = f2b(v);
        return;
    }
    idx -= 24576;
    if (idx < KH * BB) {   // act_t[ki*BB + b]: action, AA for padded steps
        int ki = idx / BB, b = idx - ki * BB;
        int n = b / SS, s = b - n * SS;
        int tt = ts[s] + ki;
        act_t[idx] = (tt < TT - 1) ? actions[n * TT + tt] : AA;
    }
}

// Weights-stationary GRU at 4 waves/SIMD.
// 192 blocks x 1024 thr (16 waves); block owns 32 rows, wave owns 16 cols x 3 gates.
// VGPR <= 128 (launch_bounds(1024,4)): wr 48 + wih 6 + acc 16 + hm 8 + misc.
// One barrier/step via double-buffered htile; actions from LDS; gi via one-hot MFMA.
__global__ void __launch_bounds__(1024, 4)
k_gru_all(const unsigned short* __restrict__ whh_s, const unsigned short* __restrict__ wihp,
          const float* __restrict__ bhh, const int* __restrict__ act_t,
          const int* __restrict__ us, const int* __restrict__ ts,
          const float* __restrict__ b_t, unsigned short* __restrict__ hpred) {
    __shared__ alignas(16) unsigned short htile[2][32][264];   // 33.8 KB double buffer
    __shared__ int act_l[32][KH];                              // 2.6 KB

    int tid = threadIdx.x, wave = tid >> 6, lane = tid & 63;
    int l15 = lane & 15, grp = lane >> 4, lk8 = grp << 3, r4 = grp << 2;
    int rb = blockIdx.x * 32;
    int u0 = us[0], u1 = us[1];
    int kmax = u0 > u1 ? u0 : u1;
    int j = wave * 16 + l15;   // this lane's single output column

    // stage actions: act_l[row][ki]
    if (tid < 32 * KH) {
        int r = tid / KH, k2 = tid - r * KH;
        act_l[r][k2] = act_t[k2 * BB + rb + r];
    }

    // weights -> registers: gate g rows [g*256 + wave*16 .. +16)
    bf16x8 wr[3][8];   // 48 VGPR
    bf16x8 wih[3];     // 6 VGPR
#pragma unroll
    for (int g = 0; g < 3; ++g) {
        int wrow = g * 256 + j;
        const unsigned short* base = &whh_s[(size_t)wrow * HH];
#pragma unroll
        for (int kk = 0; kk < 8; ++kk)
            wr[g][kk] = *reinterpret_cast<const bf16x8*>(&base[kk * 32 + lk8]);
        wih[g] = *reinterpret_cast<const bf16x8*>(&wihp[wrow * 32 + lk8]);
    }
    float bhn = SCL_N * bhh[512 + j];

    // fp32 h master: rows rt*16+r4+reg, col j
    float hm[2][4];
#pragma unroll
    for (int rt = 0; rt < 2; ++rt)
#pragma unroll
        for (int reg = 0; reg < 4; ++reg) {
            int b = rb + rt * 16 + r4 + reg;
            int n = b / SS, s = b - n * SS;
            hm[rt][reg] = b_t[(size_t)(n * TT + ts[s]) * HH + j];
        }

    // htile init: buf0 = bf16(h0)
    for (int i = tid; i < 32 * 32; i += 1024) {
        int row = i >> 5, c8 = (i & 31) << 3;
        int b = rb + row;
        int n = b / SS, s = b - n * SS;
        const float* src = &b_t[(size_t)(n * TT + ts[s]) * HH + c8];
        uint4 pk;
        pk.x = f2b(src[0]) | ((unsigned)f2b(src[1]) << 16);
        pk.y = f2b(src[2]) | ((unsigned)f2b(src[3]) << 16);
        pk.z = f2b(src[4]) | ((unsigned)f2b(src[5]) << 16);
        pk.w = f2b(src[6]) | ((unsigned)f2b(src[7]) << 16);
        *reinterpret_cast<uint4*>(&htile[0][row][c8]) = pk;
    }
    __syncthreads();

    int cur = 0;
    for (int ki = 0; ki <= kmax; ++ki) {
        int nxt = cur ^ 1;
#pragma unroll
        for (int rt = 0; rt < 2; ++rt) {
            // one-hot A-frag from LDS action (row rt*16+l15)
            int a = act_l[rt * 16 + l15][ki];
            ux4 ohu;
#pragma unroll
            for (int i = 0; i < 4; ++i) {
                int k0 = lk8 + 2 * i, k1 = k0 + 1;
                unsigned v0 = (a == k0 || k0 == AA) ? 0x3F80u : 0u;
                unsigned v1 = (a == k1 || k1 == AA) ? 0x3F80u : 0u;
                ohu[i] = v0 | (v1 << 16);
            }
            bf16x8 ohf = __builtin_bit_cast(bf16x8, ohu);

            f32x4 aR = {}, aZ = {}, aN = {}, aNI = {};
            aR  = mfma16(ohf, wih[0], aR);
            aZ  = mfma16(ohf, wih[1], aZ);
            aNI = mfma16(ohf, wih[2], aNI);
#pragma unroll
            for (int kk = 0; kk < 8; ++kk) {
                bf16x8 ah = *reinterpret_cast<const bf16x8*>(&htile[cur][rt * 16 + l15][kk * 32 + lk8]);
                aR = mfma16(ah, wr[0][kk], aR);
                aZ = mfma16(ah, wr[1][kk], aZ);
                aN = mfma16(ah, wr[2][kk], aN);
            }
#pragma unroll
            for (int reg = 0; reg < 4; ++reg) {
                int rowl = rt * 16 + r4 + reg;
                float r = rcp_f(1.f + exp2_f(aR[reg]));
                float z = rcp_f(1.f + exp2_f(aZ[reg]));
                float tv = aNI[reg] + r * (aN[reg] + bhn);
                float nv = 2.f * rcp_f(1.f + exp2_f(tv)) - 1.f;
                float h = hm[rt][reg];
                float hn = nv + z * (h - nv);
                hm[rt][reg] = hn;
                unsigned short hbv = f2b(hn);
                htile[nxt][rowl][j] = hbv;
                if (ki == u0) hpred[(size_t)(rb + rowl) * HH + j] = hbv;
                if (ki == u1) hpred[(size_t)(BB + rb + rowl) * HH + j] = hbv;
            }
        }
        __syncthreads();   // nxt fully written; cur fully read
        cur = nxt;
    }
}

// Fused 3-layer MLP + loss: 256 blocks x 48 rows. pred never leaves registers.
__device__ __forceinline__ int xsw(int row, int chunk) {
    return (row << 9) + ((chunk ^ (row & 7)) << 3);   // ushort index, 16B granules
}

__global__ void __launch_bounds__(512, 4)
k_mlp_loss(const unsigned short* __restrict__ hpred, const unsigned short* __restrict__ w1t,
           const unsigned short* __restrict__ w2t, const unsigned short* __restrict__ w3t,
           const float* __restrict__ b1, const float* __restrict__ b2,
           const float* __restrict__ b3, const float* __restrict__ z_t,
           const float* __restrict__ dones, const int* __restrict__ ts,
           const int* __restrict__ us, float* __restrict__ part) {
    __shared__ unsigned short xs[48 * 512];   // 49.2 KB
    __shared__ unsigned short zs[48 * 256];   // 24.6 KB (bf16 targets)
    __shared__ float rstat[48][8][3];         // 4.6 KB
    __shared__ float vmask[48];

    int tid = threadIdx.x, wave = tid >> 6, lane = tid & 63;
    int l15 = lane & 15, grp = lane >> 4, lk8 = grp << 3, r4 = grp << 2;
    int rb = blockIdx.x * 48;

    // per-row validity mask
    if (tid < 48) {
        int rg = rb + tid;
        int f = rg >= BB ? 1 : 0;
        int b = rg - f * BB;
        int n = b / SS, s = b - n * SS;
        int t = ts[s], u = us[f];
        float m = (t + u < TT - 1) ? 1.f : 0.f;
        if (m > 0.f) for (int jj = 0; jj <= u; ++jj) m *= (1.f - dones[n * TT + t + jj]);
        vmask[tid] = (m > 0.f) ? 1.f : 0.f;
    }
    // stage z targets -> bf16 LDS
    for (int i = tid; i < 48 * 64; i += 512) {
        int row = i >> 6, c4 = (i & 63) << 2;
        int rg = rb + row;
        int f = rg >= BB ? 1 : 0;
        int b = rg - f * BB;
        int n = b / SS, s = b - n * SS;
        int t = ts[s], u = us[f];
        uint2 pk = {0u, 0u};
        if (t + u < TT - 1) {
            float4 v = *reinterpret_cast<const float4*>(&z_t[(size_t)(n * TT + 1 + t + u) * HH + c4]);
            pk.x = f2b(v.x) | ((unsigned)f2b(v.y) << 16);
            pk.y = f2b(v.z) | ((unsigned)f2b(v.w) << 16);
        }
        *reinterpret_cast<uint2*>(&zs[row * 256 + c4]) = pk;
    }

    // Layer 1: x1 = relu(hpred @ W1 + b1), K=256
    {
        f32x4 acc[3][4] = {};
        for (int kk = 0; kk < 8; ++kk) {
            int k0 = kk * 32 + lk8;
            bf16x8 av[3];
#pragma unroll
            for (int rt = 0; rt < 3; ++rt)
                av[rt] = *reinterpret_cast<const bf16x8*>(&hpred[(size_t)(rb + rt * 16 + l15) * HH + k0]);
#pragma unroll
            for (int ct = 0; ct < 4; ++ct) {
                int col = wave * 64 + ct * 16 + l15;
                bf16x8 bv = *reinterpret_cast<const bf16x8*>(&w1t[(size_t)col * HH + k0]);
#pragma unroll
                for (int rt = 0; rt < 3; ++rt) acc[rt][ct] = mfma16(av[rt], bv, acc[rt][ct]);
            }
        }
#pragma unroll
        for (int ct = 0; ct < 4; ++ct) {
            int col = wave * 64 + ct * 16 + l15;
            float bb = b1[col];
#pragma unroll
            for (int rt = 0; rt < 3; ++rt)
#pragma unroll
                for (int reg = 0; reg < 4; ++reg)
                    xs[xsw(rt * 16 + r4 + reg, col >> 3) + (col & 7)] =
                        f2b(fmaxf(acc[rt][ct][reg] + bb, 0.f));
        }
    }
    __syncthreads();   // also covers zs/vmask staging

    // Layer 2: x2 = relu(x1 @ W2 + b2), K=512
    {
        f32x4 acc[3][4] = {};
        for (int kk = 0; kk < 16; ++kk) {
            bf16x8 av[3];
#pragma unroll
            for (int rt = 0; rt < 3; ++rt)
                av[rt] = *reinterpret_cast<const bf16x8*>(&xs[xsw(rt * 16 + l15, kk * 4 + grp)]);
#pragma unroll
            for (int ct = 0; ct < 4; ++ct) {
                int col = wave * 64 + ct * 16 + l15;
                bf16x8 bv = *reinterpret_cast<const bf16x8*>(&w2t[(size_t)col * MM + kk * 32 + lk8]);
#pragma unroll
                for (int rt = 0; rt < 3; ++rt) acc[rt][ct] = mfma16(av[rt], bv, acc[rt][ct]);
            }
        }
        __syncthreads();
#pragma unroll
        for (int ct = 0; ct < 4; ++ct) {
            int col = wave * 64 + ct * 16 + l15;
            float bb = b2[col];
#pragma unroll
            for (int rt = 0; rt < 3; ++rt)
#pragma unroll
                for (int reg = 0; reg < 4; ++reg)
                    xs[xsw(rt * 16 + r4 + reg, col >> 3) + (col & 7)] =
                        f2b(fmaxf(acc[rt][ct][reg] + bb, 0.f));
        }
    }
    __syncthreads();

    // Layer 3 + loss stats: wave owns 32 cols
    {
        f32x4 acc[3][2] = {};
        for (int kk = 0; kk < 16; ++kk) {
            bf16x8 av[3];
#pragma unroll
            for (int rt = 0; rt < 3; ++rt)
                av[rt] = *reinterpret_cast<const bf16x8*>(&xs[xsw(rt * 16 + l15, kk * 4 + grp)]);
#pragma unroll
            for (int ct = 0; ct < 2; ++ct) {
                int col = wave * 32 + ct * 16 + l15;
                bf16x8 bv = *reinterpret_cast<const bf16x8*>(&w3t[(size_t)col * MM + kk * 32 + lk8]);
#pragma unroll
                for (int rt = 0; rt < 3; ++rt) acc[rt][ct] = mfma16(av[rt], bv, acc[rt][ct]);
            }
        }
        float b3c0 = b3[wave * 32 + l15];
        float b3c1 = b3[wave * 32 + 16 + l15];
#pragma unroll
        for (int rt = 0; rt < 3; ++rt)
#pragma unroll
            for (int reg = 0; reg < 4; ++reg) {
                int row = rt * 16 + r4 + reg;
                float p0 = acc[rt][0][reg] + b3c0;
                float p1 = acc[rt][1][reg] + b3c1;
                float z0 = b2f(zs[row * 256 + wave * 32 + l15]);
                float z1 = b2f(zs[row * 256 + wave * 32 + 16 + l15]);
                float psq = p0 * p0 + p1 * p1;
                float zsq = z0 * z0 + z1 * z1;
                float pz  = p0 * z0 + p1 * z1;
#pragma unroll
                for (int o = 1; o < 16; o <<= 1) {
                    psq += __shfl_xor(psq, o);
                    zsq += __shfl_xor(zsq, o);
                    pz  += __shfl_xor(pz, o);
                }
                if (l15 == 0) {
                    rstat[row][wave][0] = psq;
                    rstat[row][wave][1] = zsq;
                    rstat[row][wave][2] = pz;
                }
            }
    }
    __syncthreads();

    // final per-row loss + block reduce (wave 0 only)
    if (tid < 64) {
        float a0 = 0.f, a1 = 0.f, a2 = 0.f;
        if (tid < 48) {
            float sp = 0.f, sz = 0.f, spz = 0.f;
#pragma unroll
            for (int w = 0; w < 8; ++w) {
                sp  += rstat[tid][w][0];
                sz  += rstat[tid][w][1];
                spz += rstat[tid][w][2];
            }
            float npn = sqrtf(sp), nzn = sqrtf(sz);
            float d = npn - 1.f;
            a2 = 0.02f * d * d;
            float mp = fmaxf(npn, 1e-8f), mz = fmaxf(nzn, 1e-8f);
            float lossr = (sp / (mp * mp) + sz / (mz * mz) - 2.f * spz / (mp * mz)) * (1.f / HH);
            float vm = vmask[tid];
            a0 = vm * lossr;
            a1 = vm;
        }
#pragma unroll
        for (int o = 1; o < 64; o <<= 1) {
            a0 += __shfl_xor(a0, o);
            a1 += __shfl_xor(a1, o);
            a2 += __shfl_xor(a2, o);
        }
        if (tid == 0) {
            part[blockIdx.x * 3 + 0] = a0;
            part[blockIdx.x * 3 + 1] = a1;
            part[blockIdx.x * 3 + 2] = a2;
        }
    }
}

// Final reduction over 256 partials.
__global__ void k_final(const float* __restrict__ part, float* out) {
    int tid = threadIdx.x, wave = tid >> 6, lane = tid & 63;
    float s0 = part[tid * 3 + 0];
    float s1 = part[tid * 3 + 1];
    float s2 = part[tid * 3 + 2];
    for (int o = 32; o; o >>= 1) {
        s0 += __shfl_xor(s0, o);
        s1 += __shfl_xor(s1, o);
        s2 += __shfl_xor(s2, o);
    }
    __shared__ float sm[4][3];
    if (lane == 0) { sm[wave][0] = s0; sm[wave][1] = s1; sm[wave][2] = s2; }
    __syncthreads();
    if (tid == 0) {
        float a = 0.f, b = 0.f, c = 0.f;
        for (int w = 0; w < 4; ++w) { a += sm[w][0]; b += sm[w][1]; c += sm[w][2]; }
        out[0] = a / fmaxf(b, 1.f) + c * (1.f / RR);
    }
}

extern "C" void kernel_launch(void* const* d_in, const int* in_sizes, int n_in,
                              void* d_out, int out_size, void* d_ws, size_t ws_size,
                              hipStream_t stream) {
    const int*   actions = (const int*)d_in[0];
    const float* dones   = (const float*)d_in[1];
    const float* b_t     = (const float*)d_in[2];
    const float* z_t     = (const float*)d_in[3];
    const int*   ts      = (const int*)d_in[4];
    const int*   us      = (const int*)d_in[5];
    const float* W_ih    = (const float*)d_in[6];
    const float* W_hh    = (const float*)d_in[7];
    const float* b_ih    = (const float*)d_in[8];
    const float* b_hh    = (const float*)d_in[9];
    const float* W1      = (const float*)d_in[10];
    const float* b1      = (const float*)d_in[11];
    const float* W2      = (const float*)d_in[12];
    const float* b2      = (const float*)d_in[13];
    const float* W3      = (const float*)d_in[14];
    const float* b3      = (const float*)d_in[15];

    char* ws = (char*)d_ws;
    int*            act_t = (int*)(ws + OFF_ACT);
    unsigned short* hpred = (unsigned short*)(ws + OFF_HPRED);
    unsigned short* whh_s = (unsigned short*)(ws + OFF_WHH);
    unsigned short* w1t   = (unsigned short*)(ws + OFF_W1T);
    unsigned short* w2t   = (unsigned short*)(ws + OFF_W2T);
    unsigned short* w3t   = (unsigned short*)(ws + OFF_W3T);
    unsigned short* wihp  = (unsigned short*)(ws + OFF_WIHP);
    float*          part  = (float*)(ws + OFF_PART);

    // total prep elements: 196608+131072+262144+131072+24576+122880 = 868352 = 3392*256
    k_prep<<<3392, 256, 0, stream>>>(W_hh, W1, W2, W3, W_ih, b_ih, b_hh, actions, ts,
                                     whh_s, w1t, w2t, w3t, wihp, act_t);
    k_gru_all<<<192, 1024, 0, stream>>>(whh_s, wihp, b_hh, act_t, us, ts, b_t, hpred);
    k_mlp_loss<<<256, 512, 0, stream>>>(hpred, w1t, w2t, w3t, b1, b2, b3,
                                        z_t, dones, ts, us, part);
    k_final<<<1, 256, 0, stream>>>(part, (float*)d_out);
}

// Round 8
// 137.822 us; speedup vs baseline: 1.1252x; 1.1252x over previous
//
#include <hip/hip_runtime.h>
#include <hip/hip_bf16.h>
#include <math.h>

// Problem constants (from setup_inputs):
#define NN 1024
#define TT 128
#define SS 6
#define FF 2
#define HH 256
#define AA 18
#define MM 512
#define KH 20
#define BB (NN*SS)        // 6144
#define RR (FF*BB)        // 12288

#define SCL_RZ (-1.44269504089f)      // -log2(e): sigmoid(x)=rcp(1+exp2(-x*log2e))
#define SCL_N  (-2.88539008178f)      // -2*log2(e): tanh(x)=2*rcp(1+exp2(-2x*log2e))-1

typedef __bf16 bf16x8 __attribute__((ext_vector_type(8)));
typedef float f32x4 __attribute__((ext_vector_type(4)));
typedef unsigned ux4 __attribute__((ext_vector_type(4)));

__device__ __forceinline__ f32x4 mfma16(bf16x8 a, bf16x8 b, f32x4 c) {
    return __builtin_amdgcn_mfma_f32_16x16x32_bf16(a, b, c, 0, 0, 0);
}
__device__ __forceinline__ unsigned short f2b(float f) {
    return __builtin_bit_cast(unsigned short, __float2bfloat16(f));
}
__device__ __forceinline__ float b2f(unsigned short u) {
    return __builtin_bit_cast(float, (unsigned)u << 16);
}
__device__ __forceinline__ float rcp_f(float x)  { return __builtin_amdgcn_rcpf(x); }
__device__ __forceinline__ float exp2_f(float x) { return __builtin_amdgcn_exp2f(x); }

// ---- ws layout (bytes) ----
#define OFF_ACT   0UL                 // KH*BB int (act_t[ki][b]) = 491,520
#define OFF_HPRED 491520UL            // RR*HH bf16 = 6,291,456
#define OFF_WHH   6782976UL           // 768*256 bf16 (pre-scaled) = 393,216
#define OFF_W1T   7176192UL           // 512*256 bf16 = 262,144
#define OFF_W2T   7438336UL           // 512*512 bf16 = 524,288
#define OFF_W3T   7962624UL           // 256*512 bf16 = 262,144
#define OFF_WIHP  8224768UL           // 768*32 bf16 (pre-scaled, bias col 18) = 49,152
#define OFF_PART  8273920UL           // 256*3 f32 = 3,072

// Prep: scaled bf16 W_hh, transposed MLP weights, scaled wih_pad, action table.
__global__ void k_prep(const float* __restrict__ Whh, const float* __restrict__ W1,
                       const float* __restrict__ W2, const float* __restrict__ W3,
                       const float* __restrict__ Wih, const float* __restrict__ bih,
                       const float* __restrict__ bhh,
                       const int* __restrict__ actions, const int* __restrict__ ts,
                       unsigned short* whh_s, unsigned short* w1t, unsigned short* w2t,
                       unsigned short* w3t, unsigned short* wihp, int* act_t) {
    int idx = blockIdx.x * 256 + threadIdx.x;
    if (idx < 196608) {   // W_hh, pre-scaled per gate
        int wrow = idx >> 8;
        float scl = (wrow < 512) ? SCL_RZ : SCL_N;
        whh_s[idx] = f2b(Whh[idx] * scl);
        return;
    }
    idx -= 196608;
    if (idx < 131072) { int m = idx >> 8, k = idx & 255; w1t[idx] = f2b(W1[k * MM + m]); return; }
    idx -= 131072;
    if (idx < 262144) { int m = idx >> 9, k = idx & 511; w2t[idx] = f2b(W2[k * MM + m]); return; }
    idx -= 262144;
    if (idx < 131072) { int c = idx >> 9, k = idx & 511; w3t[idx] = f2b(W3[k * HH + c]); return; }
    idx -= 131072;
    if (idx < 24576) {   // wih_pad[c][k]: k<18 scaled Wih; k==18 scaled bias; else 0
        int c = idx >> 5, k = idx & 31;
        int g = c >> 8;
        float scl = (g < 2) ? SCL_RZ : SCL_N;
        float v = 0.f;
        if (k < AA) v = scl * Wih[c * AA + k];
        else if (k == AA) v = scl * (bih[c] + ((g < 2) ? bhh[c] : 0.f));
        wihp[idx] = f2b(v);
        return;
    }
    idx -= 24576;
    if (idx < KH * BB) {   // act_t[ki*BB + b]: action, AA for padded steps
        int ki = idx / BB, b = idx - ki * BB;
        int n = b / SS, s = b - n * SS;
        int tt = ts[s] + ki;
        act_t[idx] = (tt < TT - 1) ? actions[n * TT + tt] : AA;
    }
}

// Weights-stationary GRU (R5 structure + one-hot gi, no tbl).
// 256 blocks x 512 thr (8 waves, 2/SIMD); block owns 24 rows (padded to 32);
// wave owns j-window [wave*32,+32) x 3 gates. W_hh+wih_pad register-resident
// (~110 VGPR); fp32 h master in regs; double-buffered htile, ONE barrier/step.
__global__ void __launch_bounds__(512, 2)
k_gru_all(const unsigned short* __restrict__ whh_s, const unsigned short* __restrict__ wihp,
          const float* __restrict__ bhh, const int* __restrict__ act_t,
          const int* __restrict__ us, const int* __restrict__ ts,
          const float* __restrict__ b_t, unsigned short* __restrict__ hpred) {
    __shared__ alignas(16) unsigned short htile[2][32][264];   // 33.8 KB double buffer
    __shared__ int act_l[32][KH];                              // 2.6 KB

    int tid = threadIdx.x, wave = tid >> 6, lane = tid & 63;
    int l15 = lane & 15, grp = lane >> 4, lk8 = grp << 3, r4 = grp << 2;
    int rb = blockIdx.x * 24;
    int u0 = us[0], u1 = us[1];
    int kmax = u0 > u1 ? u0 : u1;

    // stage actions (rows >= 24 get AA -> harmless garbage h in pad rows)
    if (tid < 32 * KH) {
        int r = tid / KH, k2 = tid - r * KH;
        act_l[r][k2] = (r < 24) ? act_t[k2 * BB + rb + r] : AA;
    }

    // weights -> registers: ct = gate*2+cj; B-col l15 -> j = wave*32 + cj*16 + l15
    bf16x8 wr[6][8];   // 96 VGPR
    bf16x8 wih[6];     // 12 VGPR
#pragma unroll
    for (int ct = 0; ct < 6; ++ct) {
        int wrow = (ct >> 1) * 256 + wave * 32 + (ct & 1) * 16 + l15;
        const unsigned short* base = &whh_s[(size_t)wrow * HH];
#pragma unroll
        for (int kk = 0; kk < 8; ++kk)
            wr[ct][kk] = *reinterpret_cast<const bf16x8*>(&base[kk * 32 + lk8]);
        wih[ct] = *reinterpret_cast<const bf16x8*>(&wihp[wrow * 32 + lk8]);
    }
    float bhn[2];
#pragma unroll
    for (int cj = 0; cj < 2; ++cj) bhn[cj] = SCL_N * bhh[512 + wave * 32 + cj * 16 + l15];

    // fp32 h master: element (rt,cj,reg) = (row rt*16+r4+reg, col wave*32+cj*16+l15)
    float hm[2][2][4];
#pragma unroll
    for (int rt = 0; rt < 2; ++rt)
#pragma unroll
        for (int cj = 0; cj < 2; ++cj)
#pragma unroll
            for (int reg = 0; reg < 4; ++reg) {
                int rowl = rt * 16 + r4 + reg;
                float v = 0.f;
                if (rowl < 24) {
                    int b = rb + rowl;
                    int n = b / SS, s = b - n * SS;
                    v = b_t[(size_t)(n * TT + ts[s]) * HH + wave * 32 + cj * 16 + l15];
                }
                hm[rt][cj][reg] = v;
            }

    // htile init: buf0 real rows = bf16(h0); pad rows and buf1 = 0
    for (int i = tid; i < 2 * 32 * 32; i += 512) {
        int buf = i >> 10, rem = i & 1023, row = rem >> 5, c8 = (rem & 31) << 3;
        uint4 pk = {0u, 0u, 0u, 0u};
        if (buf == 0 && row < 24) {
            int b = rb + row;
            int n = b / SS, s = b - n * SS;
            const float* src = &b_t[(size_t)(n * TT + ts[s]) * HH + c8];
            pk.x = f2b(src[0]) | ((unsigned)f2b(src[1]) << 16);
            pk.y = f2b(src[2]) | ((unsigned)f2b(src[3]) << 16);
            pk.z = f2b(src[4]) | ((unsigned)f2b(src[5]) << 16);
            pk.w = f2b(src[6]) | ((unsigned)f2b(src[7]) << 16);
        }
        *reinterpret_cast<uint4*>(&htile[buf][row][c8]) = pk;
    }
    __syncthreads();

    int cur = 0;
    for (int ki = 0; ki <= kmax; ++ki) {
        int nxt = cur ^ 1;
#pragma unroll
        for (int rt = 0; rt < 2; ++rt) {
            // one-hot A-frag in registers: 1.0 at k==act(row) and bias col k==18
            int a = act_l[rt * 16 + l15][ki];
            ux4 ohu;
#pragma unroll
            for (int i = 0; i < 4; ++i) {
                int k0 = lk8 + 2 * i, k1 = k0 + 1;
                unsigned v0 = (a == k0 || k0 == AA) ? 0x3F80u : 0u;
                unsigned v1 = (a == k1 || k1 == AA) ? 0x3F80u : 0u;
                ohu[i] = v0 | (v1 << 16);
            }
            bf16x8 ohf = __builtin_bit_cast(bf16x8, ohu);

            f32x4 aR[2] = {}, aZ[2] = {}, aN[2] = {}, aNI[2] = {};
            aR[0]  = mfma16(ohf, wih[0], aR[0]);   aR[1]  = mfma16(ohf, wih[1], aR[1]);
            aZ[0]  = mfma16(ohf, wih[2], aZ[0]);   aZ[1]  = mfma16(ohf, wih[3], aZ[1]);
            aNI[0] = mfma16(ohf, wih[4], aNI[0]);  aNI[1] = mfma16(ohf, wih[5], aNI[1]);
#pragma unroll
            for (int kk = 0; kk < 8; ++kk) {
                bf16x8 ah = *reinterpret_cast<const bf16x8*>(&htile[cur][rt * 16 + l15][kk * 32 + lk8]);
                aR[0] = mfma16(ah, wr[0][kk], aR[0]);
                aR[1] = mfma16(ah, wr[1][kk], aR[1]);
                aZ[0] = mfma16(ah, wr[2][kk], aZ[0]);
                aZ[1] = mfma16(ah, wr[3][kk], aZ[1]);
                aN[0] = mfma16(ah, wr[4][kk], aN[0]);
                aN[1] = mfma16(ah, wr[5][kk], aN[1]);
            }
#pragma unroll
            for (int cj = 0; cj < 2; ++cj) {
                int j2 = wave * 32 + cj * 16 + l15;
                float bhnv = bhn[cj];
#pragma unroll
                for (int reg = 0; reg < 4; ++reg) {
                    int rowl = rt * 16 + r4 + reg;
                    float r = rcp_f(1.f + exp2_f(aR[cj][reg]));
                    float z = rcp_f(1.f + exp2_f(aZ[cj][reg]));
                    float tv = aNI[cj][reg] + r * (aN[cj][reg] + bhnv);
                    float nv = 2.f * rcp_f(1.f + exp2_f(tv)) - 1.f;
                    float h = hm[rt][cj][reg];
                    float hn = nv + z * (h - nv);
                    hm[rt][cj][reg] = hn;
                    if (rowl < 24) {
                        unsigned short hbv = f2b(hn);
                        htile[nxt][rowl][j2] = hbv;
                        if (ki == u0) hpred[(size_t)(rb + rowl) * HH + j2] = hbv;
                        if (ki == u1) hpred[(size_t)(BB + rb + rowl) * HH + j2] = hbv;
                    }
                }
            }
        }
        __syncthreads();   // nxt fully written; cur fully read
        cur = nxt;
    }
}

// Fused 3-layer MLP + loss: 256 blocks x 48 rows. pred never leaves registers.
__device__ __forceinline__ int xsw(int row, int chunk) {
    return (row << 9) + ((chunk ^ (row & 7)) << 3);   // ushort index, 16B granules
}

__global__ void __launch_bounds__(512, 4)
k_mlp_loss(const unsigned short* __restrict__ hpred, const unsigned short* __restrict__ w1t,
           const unsigned short* __restrict__ w2t, const unsigned short* __restrict__ w3t,
           const float* __restrict__ b1, const float* __restrict__ b2,
           const float* __restrict__ b3, const float* __restrict__ z_t,
           const float* __restrict__ dones, const int* __restrict__ ts,
           const int* __restrict__ us, float* __restrict__ part) {
    __shared__ unsigned short xs[48 * 512];   // 49.2 KB
    __shared__ unsigned short zs[48 * 256];   // 24.6 KB (bf16 targets)
    __shared__ float rstat[48][8][3];         // 4.6 KB
    __shared__ float vmask[48];

    int tid = threadIdx.x, wave = tid >> 6, lane = tid & 63;
    int l15 = lane & 15, grp = lane >> 4, lk8 = grp << 3, r4 = grp << 2;
    int rb = blockIdx.x * 48;

    // per-row validity mask
    if (tid < 48) {
        int rg = rb + tid;
        int f = rg >= BB ? 1 : 0;
        int b = rg - f * BB;
        int n = b / SS, s = b - n * SS;
        int t = ts[s], u = us[f];
        float m = (t + u < TT - 1) ? 1.f : 0.f;
        if (m > 0.f) for (int jj = 0; jj <= u; ++jj) m *= (1.f - dones[n * TT + t + jj]);
        vmask[tid] = (m > 0.f) ? 1.f : 0.f;
    }
    // stage z targets -> bf16 LDS
    for (int i = tid; i < 48 * 64; i += 512) {
        int row = i >> 6, c4 = (i & 63) << 2;
        int rg = rb + row;
        int f = rg >= BB ? 1 : 0;
        int b = rg - f * BB;
        int n = b / SS, s = b - n * SS;
        int t = ts[s], u = us[f];
        uint2 pk = {0u, 0u};
        if (t + u < TT - 1) {
            float4 v = *reinterpret_cast<const float4*>(&z_t[(size_t)(n * TT + 1 + t + u) * HH + c4]);
            pk.x = f2b(v.x) | ((unsigned)f2b(v.y) << 16);
            pk.y = f2b(v.z) | ((unsigned)f2b(v.w) << 16);
        }
        *reinterpret_cast<uint2*>(&zs[row * 256 + c4]) = pk;
    }

    // Layer 1: x1 = relu(hpred @ W1 + b1), K=256
    {
        f32x4 acc[3][4] = {};
        for (int kk = 0; kk < 8; ++kk) {
            int k0 = kk * 32 + lk8;
            bf16x8 av[3];
#pragma unroll
            for (int rt = 0; rt < 3; ++rt)
                av[rt] = *reinterpret_cast<const bf16x8*>(&hpred[(size_t)(rb + rt * 16 + l15) * HH + k0]);
#pragma unroll
            for (int ct = 0; ct < 4; ++ct) {
                int col = wave * 64 + ct * 16 + l15;
                bf16x8 bv = *reinterpret_cast<const bf16x8*>(&w1t[(size_t)col * HH + k0]);
#pragma unroll
                for (int rt = 0; rt < 3; ++rt) acc[rt][ct] = mfma16(av[rt], bv, acc[rt][ct]);
            }
        }
#pragma unroll
        for (int ct = 0; ct < 4; ++ct) {
            int col = wave * 64 + ct * 16 + l15;
            float bb = b1[col];
#pragma unroll
            for (int rt = 0; rt < 3; ++rt)
#pragma unroll
                for (int reg = 0; reg < 4; ++reg)
                    xs[xsw(rt * 16 + r4 + reg, col >> 3) + (col & 7)] =
                        f2b(fmaxf(acc[rt][ct][reg] + bb, 0.f));
        }
    }
    __syncthreads();   // also covers zs/vmask staging

    // Layer 2: x2 = relu(x1 @ W2 + b2), K=512
    {
        f32x4 acc[3][4] = {};
        for (int kk = 0; kk < 16; ++kk) {
            bf16x8 av[3];
#pragma unroll
            for (int rt = 0; rt < 3; ++rt)
                av[rt] = *reinterpret_cast<const bf16x8*>(&xs[xsw(rt * 16 + l15, kk * 4 + grp)]);
#pragma unroll
            for (int ct = 0; ct < 4; ++ct) {
                int col = wave * 64 + ct * 16 + l15;
                bf16x8 bv = *reinterpret_cast<const bf16x8*>(&w2t[(size_t)col * MM + kk * 32 + lk8]);
#pragma unroll
                for (int rt = 0; rt < 3; ++rt) acc[rt][ct] = mfma16(av[rt], bv, acc[rt][ct]);
            }
        }
        __syncthreads();
#pragma unroll
        for (int ct = 0; ct < 4; ++ct) {
            int col = wave * 64 + ct * 16 + l15;
            float bb = b2[col];
#pragma unroll
            for (int rt = 0; rt < 3; ++rt)
#pragma unroll
                for (int reg = 0; reg < 4; ++reg)
                    xs[xsw(rt * 16 + r4 + reg, col >> 3) + (col & 7)] =
                        f2b(fmaxf(acc[rt][ct][reg] + bb, 0.f));
        }
    }
    __syncthreads();

    // Layer 3 + loss stats: wave owns 32 cols
    {
        f32x4 acc[3][2] = {};
        for (int kk = 0; kk < 16; ++kk) {
            bf16x8 av[3];
#pragma unroll
            for (int rt = 0; rt < 3; ++rt)
                av[rt] = *reinterpret_cast<const bf16x8*>(&xs[xsw(rt * 16 + l15, kk * 4 + grp)]);
#pragma unroll
            for (int ct = 0; ct < 2; ++ct) {
                int col = wave * 32 + ct * 16 + l15;
                bf16x8 bv = *reinterpret_cast<const bf16x8*>(&w3t[(size_t)col * MM + kk * 32 + lk8]);
#pragma unroll
                for (int rt = 0; rt < 3; ++rt) acc[rt][ct] = mfma16(av[rt], bv, acc[rt][ct]);
            }
        }
        float b3c0 = b3[wave * 32 + l15];
        float b3c1 = b3[wave * 32 + 16 + l15];
#pragma unroll
        for (int rt = 0; rt < 3; ++rt)
#pragma unroll
            for (int reg = 0; reg < 4; ++reg) {
                int row = rt * 16 + r4 + reg;
                float p0 = acc[rt][0][reg] + b3c0;
                float p1 = acc[rt][1][reg] + b3c1;
                float z0 = b2f(zs[row * 256 + wave * 32 + l15]);
                float z1 = b2f(zs[row * 256 + wave * 32 + 16 + l15]);
                float psq = p0 * p0 + p1 * p1;
                float zsq = z0 * z0 + z1 * z1;
                float pz  = p0 * z0 + p1 * z1;
#pragma unroll
                for (int o = 1; o < 16; o <<= 1) {
                    psq += __shfl_xor(psq, o);
                    zsq += __shfl_xor(zsq, o);
                    pz  += __shfl_xor(pz, o);
                }
                if (l15 == 0) {
                    rstat[row][wave][0] = psq;
                    rstat[row][wave][1] = zsq;
                    rstat[row][wave][2] = pz;
                }
            }
    }
    __syncthreads();

    // final per-row loss + block reduce (wave 0 only)
    if (tid < 64) {
        float a0 = 0.f, a1 = 0.f, a2 = 0.f;
        if (tid < 48) {
            float sp = 0.f, sz = 0.f, spz = 0.f;
#pragma unroll
            for (int w = 0; w < 8; ++w) {
                sp  += rstat[tid][w][0];
                sz  += rstat[tid][w][1];
                spz += rstat[tid][w][2];
            }
            float npn = sqrtf(sp), nzn = sqrtf(sz);
            float d = npn - 1.f;
            a2 = 0.02f * d * d;
            float mp = fmaxf(npn, 1e-8f), mz = fmaxf(nzn, 1e-8f);
            float lossr = (sp / (mp * mp) + sz / (mz * mz) - 2.f * spz / (mp * mz)) * (1.f / HH);
            float vm = vmask[tid];
            a0 = vm * lossr;
            a1 = vm;
        }
#pragma unroll
        for (int o = 1; o < 64; o <<= 1) {
            a0 += __shfl_xor(a0, o);
            a1 += __shfl_xor(a1, o);
            a2 += __shfl_xor(a2, o);
        }
        if (tid == 0) {
            part[blockIdx.x * 3 + 0] = a0;
            part[blockIdx.x * 3 + 1] = a1;
            part[blockIdx.x * 3 + 2] = a2;
        }
    }
}

// Final reduction over 256 partials.
__global__ void k_final(const float* __restrict__ part, float* out) {
    int tid = threadIdx.x, wave = tid >> 6, lane = tid & 63;
    float s0 = part[tid * 3 + 0];
    float s1 = part[tid * 3 + 1];
    float s2 = part[tid * 3 + 2];
    for (int o = 32; o; o >>= 1) {
        s0 += __shfl_xor(s0, o);
        s1 += __shfl_xor(s1, o);
        s2 += __shfl_xor(s2, o);
    }
    __shared__ float sm[4][3];
    if (lane == 0) { sm[wave][0] = s0; sm[wave][1] = s1; sm[wave][2] = s2; }
    __syncthreads();
    if (tid == 0) {
        float a = 0.f, b = 0.f, c = 0.f;
        for (int w = 0; w < 4; ++w) { a += sm[w][0]; b += sm[w][1]; c += sm[w][2]; }
        out[0] = a / fmaxf(b, 1.f) + c * (1.f / RR);
    }
}

extern "C" void kernel_launch(void* const* d_in, const int* in_sizes, int n_in,
                              void* d_out, int out_size, void* d_ws, size_t ws_size,
                              hipStream_t stream) {
    const int*   actions = (const int*)d_in[0];
    const float* dones   = (const float*)d_in[1];
    const float* b_t     = (const float*)d_in[2];
    const float* z_t     = (const float*)d_in[3];
    const int*   ts      = (const int*)d_in[4];
    const int*   us      = (const int*)d_in[5];
    const float* W_ih    = (const float*)d_in[6];
    const float* W_hh    = (const float*)d_in[7];
    const float* b_ih    = (const float*)d_in[8];
    const float* b_hh    = (const float*)d_in[9];
    const float* W1      = (const float*)d_in[10];
    const float* b1      = (const float*)d_in[11];
    const float* W2      = (const float*)d_in[12];
    const float* b2      = (const float*)d_in[13];
    const float* W3      = (const float*)d_in[14];
    const float* b3      = (const float*)d_in[15];

    char* ws = (char*)d_ws;
    int*            act_t = (int*)(ws + OFF_ACT);
    unsigned short* hpred = (unsigned short*)(ws + OFF_HPRED);
    unsigned short* whh_s = (unsigned short*)(ws + OFF_WHH);
    unsigned short* w1t   = (unsigned short*)(ws + OFF_W1T);
    unsigned short* w2t   = (unsigned short*)(ws + OFF_W2T);
    unsigned short* w3t   = (unsigned short*)(ws + OFF_W3T);
    unsigned short* wihp  = (unsigned short*)(ws + OFF_WIHP);
    float*          part  = (float*)(ws + OFF_PART);

    // total prep elements: 196608+131072+262144+131072+24576+122880 = 868352 = 3392*256
    k_prep<<<3392, 256, 0, stream>>>(W_hh, W1, W2, W3, W_ih, b_ih, b_hh, actions, ts,
                                     whh_s, w1t, w2t, w3t, wihp, act_t);
    k_gru_all<<<256, 512, 0, stream>>>(whh_s, wihp, b_hh, act_t, us, ts, b_t, hpred);
    k_mlp_loss<<<256, 512, 0, stream>>>(hpred, w1t, w2t, w3t, b1, b2, b3,
                                        z_t, dones, ts, us, part);
    k_final<<<1, 256, 0, stream>>>(part, (float*)d_out);
}

// Round 9
// 125.208 us; speedup vs baseline: 1.2385x; 1.1007x over previous
//
#include <hip/hip_runtime.h>
#include <hip/hip_bf16.h>
#include <math.h>

// Problem constants (from setup_inputs):
#define NN 1024
#define TT 128
#define SS 6
#define FF 2
#define HH 256
#define AA 18
#define MM 512
#define KH 20
#define BB (NN*SS)        // 6144
#define RR (FF*BB)        // 12288

#define SCL_RZ (-1.44269504089f)      // -log2(e): sigmoid(x)=rcp(1+exp2(-x*log2e))
#define SCL_N  (-2.88539008178f)      // -2*log2(e): tanh(x)=2*rcp(1+exp2(-2x*log2e))-1
#define TBL_STRIDE 784                // 768 + 16 pad f32 -> odd-bank shift per action row

typedef __bf16 bf16x8 __attribute__((ext_vector_type(8)));
typedef float f32x4 __attribute__((ext_vector_type(4)));

__device__ __forceinline__ f32x4 mfma16(bf16x8 a, bf16x8 b, f32x4 c) {
    return __builtin_amdgcn_mfma_f32_16x16x32_bf16(a, b, c, 0, 0, 0);
}
__device__ __forceinline__ unsigned short f2b(float f) {
    return __builtin_bit_cast(unsigned short, __float2bfloat16(f));
}
__device__ __forceinline__ float b2f(unsigned short u) {
    return __builtin_bit_cast(float, (unsigned)u << 16);
}
__device__ __forceinline__ float rcp_f(float x)  { return __builtin_amdgcn_rcpf(x); }
__device__ __forceinline__ float exp2_f(float x) { return __builtin_amdgcn_exp2f(x); }

// ---- ws layout (bytes) ----
#define OFF_ACT   0UL                 // BB*KH int (act[b][k]) = 491,520
#define OFF_HPRED 491520UL            // RR*HH bf16 = 6,291,456
#define OFF_WHH   6782976UL           // 768*256 bf16 (pre-scaled) = 393,216
#define OFF_W1T   7176192UL           // 512*256 bf16 = 262,144
#define OFF_W2T   7438336UL           // 512*512 bf16 = 524,288
#define OFF_W3T   7962624UL           // 256*512 bf16 = 262,144
#define OFF_TBL   8224768UL           // 19*784 f32 = 59,584 (gi lookup, biases+scale folded)
#define OFF_PART  8284352UL           // 256*3 f32 = 3,072

// Prep: scaled bf16 W_hh, transposed MLP weights, gi lookup table, action table.
__global__ void k_prep(const float* __restrict__ Whh, const float* __restrict__ W1,
                       const float* __restrict__ W2, const float* __restrict__ W3,
                       const float* __restrict__ Wih, const float* __restrict__ bih,
                       const float* __restrict__ bhh,
                       const int* __restrict__ actions, const int* __restrict__ ts,
                       unsigned short* whh_s, unsigned short* w1t, unsigned short* w2t,
                       unsigned short* w3t, float* tbl, int* act) {
    int idx = blockIdx.x * 256 + threadIdx.x;
    if (idx < 196608) {   // W_hh, pre-scaled per gate
        int wrow = idx >> 8;
        float scl = (wrow < 512) ? SCL_RZ : SCL_N;
        whh_s[idx] = f2b(Whh[idx] * scl);
        return;
    }
    idx -= 196608;
    if (idx < 131072) { int m = idx >> 8, k = idx & 255; w1t[idx] = f2b(W1[k * MM + m]); return; }
    idx -= 131072;
    if (idx < 262144) { int m = idx >> 9, k = idx & 511; w2t[idx] = f2b(W2[k * MM + m]); return; }
    idx -= 262144;
    if (idx < 131072) { int c = idx >> 9, k = idx & 511; w3t[idx] = f2b(W3[k * HH + c]); return; }
    idx -= 131072;
    if (idx < 19 * TBL_STRIDE) {   // tbl[a][g*256+j] = scl_g*(Wih[g*256+j][a] + bih + (g<2)*bhh)
        int a = idx / TBL_STRIDE, rem = idx - a * TBL_STRIDE;
        float v = 0.f;
        if (rem < 768) {
            int g = rem >> 8;
            float scl = (g < 2) ? SCL_RZ : SCL_N;
            float w = (a < AA) ? Wih[rem * AA + a] : 0.f;
            v = scl * (w + bih[rem] + ((g < 2) ? bhh[rem] : 0.f));
        }
        tbl[idx] = v;
        return;
    }
    idx -= 19 * TBL_STRIDE;
    if (idx < BB * KH) {   // act[b][k]: action index, AA for padded steps
        int b = idx / KH, k = idx - b * KH;
        int n = b / SS, s = b - n * SS;
        int tt = ts[s] + k;
        act[idx] = (tt < TT - 1) ? actions[n * TT + tt] : AA;
    }
}

// Persistent weights-stationary GRU (R4-best config, verbatim):
// 384 blocks x 512 thr; block owns 16 rows; wave owns j-window [wave*32,+32) x 3 gates.
// W_hh register-resident (wr[6][8] = 96 VGPR); fp32 h master in regs; gi via LDS tbl.
__global__ void __launch_bounds__(512, 2)
k_gru_all(const unsigned short* __restrict__ whh_s, const float* __restrict__ tblg,
          const float* __restrict__ bhh, const int* __restrict__ actg,
          const int* __restrict__ us, const int* __restrict__ ts,
          const float* __restrict__ b_t, unsigned short* __restrict__ hpred) {
    __shared__ float tbl[19 * TBL_STRIDE];          // 59.6 KB
    __shared__ int act_l[16][KH];                   // 1.25 KB
    __shared__ unsigned short htile[16][264];       // 8.4 KB (+8 pad)

    int tid = threadIdx.x, wave = tid >> 6, lane = tid & 63;
    int l15 = lane & 15, grp = lane >> 4, lk8 = grp << 3, r4 = grp << 2;
    int rb = blockIdx.x * 16;
    int u0 = us[0], u1 = us[1];
    int kmax = u0 > u1 ? u0 : u1;

    // stage lookup table + actions to LDS
    for (int i = tid; i < 19 * TBL_STRIDE / 4; i += 512)
        reinterpret_cast<float4*>(tbl)[i] = reinterpret_cast<const float4*>(tblg)[i];
    if (tid < 16 * KH) {
        int r = tid / KH, k = tid - r * KH;
        act_l[r][k] = actg[(rb + r) * KH + k];
    }

    // weights -> registers: wave owns j-window [wave*32, wave*32+32), 3 gates.
    // ct: {0,1}=r(cj0,1) {2,3}=z {4,5}=n; B-frag col = l15 -> j = wave*32+(ct&1)*16+l15
    bf16x8 wr[6][8];
#pragma unroll
    for (int ct = 0; ct < 6; ++ct) {
        int wrow = (ct >> 1) * 256 + wave * 32 + (ct & 1) * 16 + l15;
        const unsigned short* base = &whh_s[(size_t)wrow * HH];
#pragma unroll
        for (int kk = 0; kk < 8; ++kk)
            wr[ct][kk] = *reinterpret_cast<const bf16x8*>(&base[kk * 32 + lk8]);
    }

    // fp32 h master: element (cj,reg) = (row r4+reg, col wave*32+cj*16+l15)
    float hm[2][4];
#pragma unroll
    for (int cj = 0; cj < 2; ++cj)
#pragma unroll
        for (int reg = 0; reg < 4; ++reg) {
            int b = rb + r4 + reg;
            int n = b / SS, s = b - n * SS;
            hm[cj][reg] = b_t[(size_t)(n * TT + ts[s]) * HH + wave * 32 + cj * 16 + l15];
        }
    float bhn[2];
#pragma unroll
    for (int cj = 0; cj < 2; ++cj) bhn[cj] = SCL_N * bhh[512 + wave * 32 + cj * 16 + l15];

    // initial htile = bf16(h0): one 8-col chunk per thread
    {
        int row = tid >> 5, c8 = (tid & 31) << 3;
        int b = rb + row;
        int n = b / SS, s = b - n * SS;
        const float* src = &b_t[(size_t)(n * TT + ts[s]) * HH + c8];
        uint4 pk;
        pk.x = f2b(src[0]) | ((unsigned)f2b(src[1]) << 16);
        pk.y = f2b(src[2]) | ((unsigned)f2b(src[3]) << 16);
        pk.z = f2b(src[4]) | ((unsigned)f2b(src[5]) << 16);
        pk.w = f2b(src[6]) | ((unsigned)f2b(src[7]) << 16);
        *reinterpret_cast<uint4*>(&htile[row][c8]) = pk;
    }
    __syncthreads();

    for (int ki = 0; ki <= kmax; ++ki) {
        // gh = h @ Whh_scaled^T : all operands in regs/LDS
        f32x4 aR[2] = {}, aZ[2] = {}, aN[2] = {};
#pragma unroll
        for (int kk = 0; kk < 8; ++kk) {
            bf16x8 ah = *reinterpret_cast<const bf16x8*>(&htile[l15][kk * 32 + lk8]);
            aR[0] = mfma16(ah, wr[0][kk], aR[0]);
            aR[1] = mfma16(ah, wr[1][kk], aR[1]);
            aZ[0] = mfma16(ah, wr[2][kk], aZ[0]);
            aZ[1] = mfma16(ah, wr[3][kk], aZ[1]);
            aN[0] = mfma16(ah, wr[4][kk], aN[0]);
            aN[1] = mfma16(ah, wr[5][kk], aN[1]);
        }
        __syncthreads();   // all htile reads done

        // gates + update; gi via LDS lookup (biases + exp2-scale pre-folded)
#pragma unroll
        for (int cj = 0; cj < 2; ++cj) {
            int j2 = wave * 32 + cj * 16 + l15;
            float bhnv = bhn[cj];
#pragma unroll
            for (int reg = 0; reg < 4; ++reg) {
                int row = r4 + reg;
                const float* tb = &tbl[act_l[row][ki] * TBL_STRIDE];
                float r = rcp_f(1.f + exp2_f(aR[cj][reg] + tb[j2]));
                float z = rcp_f(1.f + exp2_f(aZ[cj][reg] + tb[256 + j2]));
                float ghn = aN[cj][reg] + bhnv;
                float nv = 2.f * rcp_f(1.f + exp2_f(tb[512 + j2] + r * ghn)) - 1.f;
                float h = hm[cj][reg];
                float hn2 = nv + z * (h - nv);
                hm[cj][reg] = hn2;
                unsigned short hbv = f2b(hn2);
                htile[row][j2] = hbv;
                if (ki == u0) hpred[(size_t)(rb + row) * HH + j2] = hbv;
                if (ki == u1) hpred[(size_t)(BB + rb + row) * HH + j2] = hbv;
            }
        }
        __syncthreads();   // htile writes visible before next step's reads
    }
}

// Fused 3-layer MLP + loss: 256 blocks x 48 rows. pred never leaves registers.
// loss row needs only {sum p^2, sum z^2, sum p.z}: per-wave shfl partials + LDS reduce.
__device__ __forceinline__ int xsw(int row, int chunk) {
    return (row << 9) + ((chunk ^ (row & 7)) << 3);   // ushort index, 16B granules
}

__global__ void __launch_bounds__(512, 4)
k_mlp_loss(const unsigned short* __restrict__ hpred, const unsigned short* __restrict__ w1t,
           const unsigned short* __restrict__ w2t, const unsigned short* __restrict__ w3t,
           const float* __restrict__ b1, const float* __restrict__ b2,
           const float* __restrict__ b3, const float* __restrict__ z_t,
           const float* __restrict__ dones, const int* __restrict__ ts,
           const int* __restrict__ us, float* __restrict__ part) {
    __shared__ unsigned short xs[48 * 512];   // 49.2 KB
    __shared__ unsigned short zs[48 * 256];   // 24.6 KB (bf16 targets)
    __shared__ float rstat[48][8][3];         // 4.6 KB
    __shared__ float vmask[48];

    int tid = threadIdx.x, wave = tid >> 6, lane = tid & 63;
    int l15 = lane & 15, grp = lane >> 4, lk8 = grp << 3, r4 = grp << 2;
    int rb = blockIdx.x * 48;

    // per-row validity mask
    if (tid < 48) {
        int rg = rb + tid;
        int f = rg >= BB ? 1 : 0;
        int b = rg - f * BB;
        int n = b / SS, s = b - n * SS;
        int t = ts[s], u = us[f];
        float m = (t + u < TT - 1) ? 1.f : 0.f;
        if (m > 0.f) for (int jj = 0; jj <= u; ++jj) m *= (1.f - dones[n * TT + t + jj]);
        vmask[tid] = (m > 0.f) ? 1.f : 0.f;
    }
    // stage z targets -> bf16 LDS
    for (int i = tid; i < 48 * 64; i += 512) {
        int row = i >> 6, c4 = (i & 63) << 2;
        int rg = rb + row;
        int f = rg >= BB ? 1 : 0;
        int b = rg - f * BB;
        int n = b / SS, s = b - n * SS;
        int t = ts[s], u = us[f];
        uint2 pk = {0u, 0u};
        if (t + u < TT - 1) {
            float4 v = *reinterpret_cast<const float4*>(&z_t[(size_t)(n * TT + 1 + t + u) * HH + c4]);
            pk.x = f2b(v.x) | ((unsigned)f2b(v.y) << 16);
            pk.y = f2b(v.z) | ((unsigned)f2b(v.w) << 16);
        }
        *reinterpret_cast<uint2*>(&zs[row * 256 + c4]) = pk;
    }

    // Layer 1: x1 = relu(hpred @ W1 + b1), K=256
    {
        f32x4 acc[3][4] = {};
        for (int kk = 0; kk < 8; ++kk) {
            int k0 = kk * 32 + lk8;
            bf16x8 av[3];
#pragma unroll
            for (int rt = 0; rt < 3; ++rt)
                av[rt] = *reinterpret_cast<const bf16x8*>(&hpred[(size_t)(rb + rt * 16 + l15) * HH + k0]);
#pragma unroll
            for (int ct = 0; ct < 4; ++ct) {
                int col = wave * 64 + ct * 16 + l15;
                bf16x8 bv = *reinterpret_cast<const bf16x8*>(&w1t[(size_t)col * HH + k0]);
#pragma unroll
                for (int rt = 0; rt < 3; ++rt) acc[rt][ct] = mfma16(av[rt], bv, acc[rt][ct]);
            }
        }
#pragma unroll
        for (int ct = 0; ct < 4; ++ct) {
            int col = wave * 64 + ct * 16 + l15;
            float bb = b1[col];
#pragma unroll
            for (int rt = 0; rt < 3; ++rt)
#pragma unroll
                for (int reg = 0; reg < 4; ++reg)
                    xs[xsw(rt * 16 + r4 + reg, col >> 3) + (col & 7)] =
                        f2b(fmaxf(acc[rt][ct][reg] + bb, 0.f));
        }
    }
    __syncthreads();   // also covers zs/vmask staging

    // Layer 2: x2 = relu(x1 @ W2 + b2), K=512
    {
        f32x4 acc[3][4] = {};
        for (int kk = 0; kk < 16; ++kk) {
            bf16x8 av[3];
#pragma unroll
            for (int rt = 0; rt < 3; ++rt)
                av[rt] = *reinterpret_cast<const bf16x8*>(&xs[xsw(rt * 16 + l15, kk * 4 + grp)]);
#pragma unroll
            for (int ct = 0; ct < 4; ++ct) {
                int col = wave * 64 + ct * 16 + l15;
                bf16x8 bv = *reinterpret_cast<const bf16x8*>(&w2t[(size_t)col * MM + kk * 32 + lk8]);
#pragma unroll
                for (int rt = 0; rt < 3; ++rt) acc[rt][ct] = mfma16(av[rt], bv, acc[rt][ct]);
            }
        }
        __syncthreads();
#pragma unroll
        for (int ct = 0; ct < 4; ++ct) {
            int col = wave * 64 + ct * 16 + l15;
            float bb = b2[col];
#pragma unroll
            for (int rt = 0; rt < 3; ++rt)
#pragma unroll
                for (int reg = 0; reg < 4; ++reg)
                    xs[xsw(rt * 16 + r4 + reg, col >> 3) + (col & 7)] =
                        f2b(fmaxf(acc[rt][ct][reg] + bb, 0.f));
        }
    }
    __syncthreads();

    // Layer 3 + loss stats: wave owns 32 cols
    {
        f32x4 acc[3][2] = {};
        for (int kk = 0; kk < 16; ++kk) {
            bf16x8 av[3];
#pragma unroll
            for (int rt = 0; rt < 3; ++rt)
                av[rt] = *reinterpret_cast<const bf16x8*>(&xs[xsw(rt * 16 + l15, kk * 4 + grp)]);
#pragma unroll
            for (int ct = 0; ct < 2; ++ct) {
                int col = wave * 32 + ct * 16 + l15;
                bf16x8 bv = *reinterpret_cast<const bf16x8*>(&w3t[(size_t)col * MM + kk * 32 + lk8]);
#pragma unroll
                for (int rt = 0; rt < 3; ++rt) acc[rt][ct] = mfma16(av[rt], bv, acc[rt][ct]);
            }
        }
        float b3c0 = b3[wave * 32 + l15];
        float b3c1 = b3[wave * 32 + 16 + l15];
#pragma unroll
        for (int rt = 0; rt < 3; ++rt)
#pragma unroll
            for (int reg = 0; reg < 4; ++reg) {
                int row = rt * 16 + r4 + reg;
                float p0 = acc[rt][0][reg] + b3c0;
                float p1 = acc[rt][1][reg] + b3c1;
                float z0 = b2f(zs[row * 256 + wave * 32 + l15]);
                float z1 = b2f(zs[row * 256 + wave * 32 + 16 + l15]);
                float psq = p0 * p0 + p1 * p1;
                float zsq = z0 * z0 + z1 * z1;
                float pz  = p0 * z0 + p1 * z1;
#pragma unroll
                for (int o = 1; o < 16; o <<= 1) {
                    psq += __shfl_xor(psq, o);
                    zsq += __shfl_xor(zsq, o);
                    pz  += __shfl_xor(pz, o);
                }
                if (l15 == 0) {
                    rstat[row][wave][0] = psq;
                    rstat[row][wave][1] = zsq;
                    rstat[row][wave][2] = pz;
                }
            }
    }
    __syncthreads();

    // final per-row loss + block reduce (wave 0 only)
    if (tid < 64) {
        float a0 = 0.f, a1 = 0.f, a2 = 0.f;
        if (tid < 48) {
            float sp = 0.f, sz = 0.f, spz = 0.f;
#pragma unroll
            for (int w = 0; w < 8; ++w) {
                sp  += rstat[tid][w][0];
                sz  += rstat[tid][w][1];
                spz += rstat[tid][w][2];
            }
            float npn = sqrtf(sp), nzn = sqrtf(sz);
            float d = npn - 1.f;
            a2 = 0.02f * d * d;
            float mp = fmaxf(npn, 1e-8f), mz = fmaxf(nzn, 1e-8f);
            float lossr = (sp / (mp * mp) + sz / (mz * mz) - 2.f * spz / (mp * mz)) * (1.f / HH);
            float vm = vmask[tid];
            a0 = vm * lossr;
            a1 = vm;
        }
#pragma unroll
        for (int o = 1; o < 64; o <<= 1) {
            a0 += __shfl_xor(a0, o);
            a1 += __shfl_xor(a1, o);
            a2 += __shfl_xor(a2, o);
        }
        if (tid == 0) {
            part[blockIdx.x * 3 + 0] = a0;
            part[blockIdx.x * 3 + 1] = a1;
            part[blockIdx.x * 3 + 2] = a2;
        }
    }
}

// Final reduction over 256 partials.
__global__ void k_final(const float* __restrict__ part, float* out) {
    int tid = threadIdx.x, wave = tid >> 6, lane = tid & 63;
    float s0 = part[tid * 3 + 0];
    float s1 = part[tid * 3 + 1];
    float s2 = part[tid * 3 + 2];
    for (int o = 32; o; o >>= 1) {
        s0 += __shfl_xor(s0, o);
        s1 += __shfl_xor(s1, o);
        s2 += __shfl_xor(s2, o);
    }
    __shared__ float sm[4][3];
    if (lane == 0) { sm[wave][0] = s0; sm[wave][1] = s1; sm[wave][2] = s2; }
    __syncthreads();
    if (tid == 0) {
        float a = 0.f, b = 0.f, c = 0.f;
        for (int w = 0; w < 4; ++w) { a += sm[w][0]; b += sm[w][1]; c += sm[w][2]; }
        out[0] = a / fmaxf(b, 1.f) + c * (1.f / RR);
    }
}

extern "C" void kernel_launch(void* const* d_in, const int* in_sizes, int n_in,
                              void* d_out, int out_size, void* d_ws, size_t ws_size,
                              hipStream_t stream) {
    const int*   actions = (const int*)d_in[0];
    const float* dones   = (const float*)d_in[1];
    const float* b_t     = (const float*)d_in[2];
    const float* z_t     = (const float*)d_in[3];
    const int*   ts      = (const int*)d_in[4];
    const int*   us      = (const int*)d_in[5];
    const float* W_ih    = (const float*)d_in[6];
    const float* W_hh    = (const float*)d_in[7];
    const float* b_ih    = (const float*)d_in[8];
    const float* b_hh    = (const float*)d_in[9];
    const float* W1      = (const float*)d_in[10];
    const float* b1      = (const float*)d_in[11];
    const float* W2      = (const float*)d_in[12];
    const float* b2      = (const float*)d_in[13];
    const float* W3      = (const float*)d_in[14];
    const float* b3      = (const float*)d_in[15];

    char* ws = (char*)d_ws;
    int*            act   = (int*)(ws + OFF_ACT);
    unsigned short* hpred = (unsigned short*)(ws + OFF_HPRED);
    unsigned short* whh_s = (unsigned short*)(ws + OFF_WHH);
    unsigned short* w1t   = (unsigned short*)(ws + OFF_W1T);
    unsigned short* w2t   = (unsigned short*)(ws + OFF_W2T);
    unsigned short* w3t   = (unsigned short*)(ws + OFF_W3T);
    float*          tbl   = (float*)(ws + OFF_TBL);
    float*          part  = (float*)(ws + OFF_PART);

    // total prep elements: 196608+131072+262144+131072+14896+122880 = 858672 -> 3355 blocks
    k_prep<<<3355, 256, 0, stream>>>(W_hh, W1, W2, W3, W_ih, b_ih, b_hh, actions, ts,
                                     whh_s, w1t, w2t, w3t, tbl, act);
    k_gru_all<<<384, 512, 0, stream>>>(whh_s, tbl, b_hh, act, us, ts, b_t, hpred);
    k_mlp_loss<<<256, 512, 0, stream>>>(hpred, w1t, w2t, w3t, b1, b2, b3,
                                        z_t, dones, ts, us, part);
    k_final<<<1, 256, 0, stream>>>(part, (float*)d_out);
}

// Round 10
// 116.382 us; speedup vs baseline: 1.3324x; 1.0758x over previous
//
#include <hip/hip_runtime.h>
#include <hip/hip_bf16.h>
#include <math.h>

// Problem constants (from setup_inputs):
#define NN 1024
#define TT 128
#define SS 6
#define FF 2
#define HH 256
#define AA 18
#define MM 512
#define KH 20
#define BB (NN*SS)        // 6144
#define RR (FF*BB)        // 12288

#define SCL_RZ (-1.44269504089f)      // -log2(e): sigmoid(x)=rcp(1+exp2(-x*log2e))
#define SCL_N  (-2.88539008178f)      // -2*log2(e): tanh(x)=2*rcp(1+exp2(-2x*log2e))-1
#define TBLP_STRIDE 129               // uint4 stride: +16B bank shift per action row

typedef __bf16 bf16x8 __attribute__((ext_vector_type(8)));
typedef float f32x4 __attribute__((ext_vector_type(4)));

__device__ __forceinline__ f32x4 mfma16(bf16x8 a, bf16x8 b, f32x4 c) {
    return __builtin_amdgcn_mfma_f32_16x16x32_bf16(a, b, c, 0, 0, 0);
}
__device__ __forceinline__ unsigned short f2b(float f) {
    return __builtin_bit_cast(unsigned short, __float2bfloat16(f));
}
__device__ __forceinline__ float b2f(unsigned short u) {
    return __builtin_bit_cast(float, (unsigned)u << 16);
}
__device__ __forceinline__ float blo(unsigned u) {   // low bf16 -> f32
    return __builtin_bit_cast(float, u << 16);
}
__device__ __forceinline__ float bhi(unsigned u) {   // high bf16 -> f32
    return __builtin_bit_cast(float, u & 0xffff0000u);
}
__device__ __forceinline__ float rcp_f(float x)  { return __builtin_amdgcn_rcpf(x); }
__device__ __forceinline__ float exp2_f(float x) { return __builtin_amdgcn_exp2f(x); }

// ---- ws layout (bytes) ----
#define OFF_ACT   0UL                 // BB*KH int (act[b][k]) = 491,520
#define OFF_HPRED 491520UL            // RR*HH bf16 = 6,291,456
#define OFF_WHH   6782976UL           // 768*256 bf16 (pre-scaled) = 393,216
#define OFF_W1T   7176192UL           // 512*256 bf16 = 262,144
#define OFF_W2T   7438336UL           // 512*512 bf16 = 524,288
#define OFF_W3T   7962624UL           // 256*512 bf16 = 262,144
#define OFF_TBL   8224768UL           // 19*129 uint4 = 39,216 (packed bf16 gi pairs)
#define OFF_PART  8264000UL           // 256*3 f32 = 3,072

// Prep: scaled bf16 W_hh, transposed MLP weights, packed gi pair-table, action table.
__global__ void k_prep(const float* __restrict__ Whh, const float* __restrict__ W1,
                       const float* __restrict__ W2, const float* __restrict__ W3,
                       const float* __restrict__ Wih, const float* __restrict__ bih,
                       const float* __restrict__ bhh,
                       const int* __restrict__ actions, const int* __restrict__ ts,
                       unsigned short* whh_s, unsigned short* w1t, unsigned short* w2t,
                       unsigned short* w3t, uint4* tblp, int* act) {
    int idx = blockIdx.x * 256 + threadIdx.x;
    if (idx < 196608) {   // W_hh, pre-scaled per gate
        int wrow = idx >> 8;
        float scl = (wrow < 512) ? SCL_RZ : SCL_N;
        whh_s[idx] = f2b(Whh[idx] * scl);
        return;
    }
    idx -= 196608;
    if (idx < 131072) { int m = idx >> 8, k = idx & 255; w1t[idx] = f2b(W1[k * MM + m]); return; }
    idx -= 131072;
    if (idx < 262144) { int m = idx >> 9, k = idx & 511; w2t[idx] = f2b(W2[k * MM + m]); return; }
    idx -= 262144;
    if (idx < 131072) { int c = idx >> 9, k = idx & 511; w3t[idx] = f2b(W3[k * HH + c]); return; }
    idx -= 131072;
    if (idx < 19 * TBLP_STRIDE) {   // tblp[a][jp]: packed bf16 {r0r1, z0z1, n0n1, 0}
        int a = idx / TBLP_STRIDE, jp = idx - a * TBLP_STRIDE;
        uint4 o = {0u, 0u, 0u, 0u};
        if (jp < 128) {
            int j0 = jp * 2, j1 = j0 + 1;
            float wr0 = (a < AA) ? Wih[j0 * AA + a] : 0.f;
            float wr1 = (a < AA) ? Wih[j1 * AA + a] : 0.f;
            float wz0 = (a < AA) ? Wih[(256 + j0) * AA + a] : 0.f;
            float wz1 = (a < AA) ? Wih[(256 + j1) * AA + a] : 0.f;
            float wn0 = (a < AA) ? Wih[(512 + j0) * AA + a] : 0.f;
            float wn1 = (a < AA) ? Wih[(512 + j1) * AA + a] : 0.f;
            float r0 = SCL_RZ * (wr0 + bih[j0] + bhh[j0]);
            float r1 = SCL_RZ * (wr1 + bih[j1] + bhh[j1]);
            float z0 = SCL_RZ * (wz0 + bih[256 + j0] + bhh[256 + j0]);
            float z1 = SCL_RZ * (wz1 + bih[256 + j1] + bhh[256 + j1]);
            float n0 = SCL_N * (wn0 + bih[512 + j0]);
            float n1 = SCL_N * (wn1 + bih[512 + j1]);
            o.x = (unsigned)f2b(r0) | ((unsigned)f2b(r1) << 16);
            o.y = (unsigned)f2b(z0) | ((unsigned)f2b(z1) << 16);
            o.z = (unsigned)f2b(n0) | ((unsigned)f2b(n1) << 16);
        }
        tblp[idx] = o;
        return;
    }
    idx -= 19 * TBLP_STRIDE;
    if (idx < BB * KH) {   // act[b][k]: action index, AA for padded steps
        int b = idx / KH, k = idx - b * KH;
        int n = b / SS, s = b - n * SS;
        int tt = ts[s] + k;
        act[idx] = (tt < TT - 1) ? actions[n * TT + tt] : AA;
    }
}

// Weights-stationary GRU, LDS-minimized:
// 256 blocks x 512 thr; block owns 24 rows (pad to 32); wave owns 32-col window
// as 16 adjacent EVEN/ODD pairs (lane l15 -> cols j0=wave*32+2*l15, j0+1).
// W_hh register-resident (192 VGPR); gi via ONE ds_read_b128 per pair (packed bf16);
// h master packed-bf16 in regs; u32-packed h writes; dbuf htile, 1 barrier/step.
__global__ void __launch_bounds__(512, 2)
k_gru_all(const unsigned short* __restrict__ whh_s, const uint4* __restrict__ tblpg,
          const float* __restrict__ bhh, const int* __restrict__ actg,
          const int* __restrict__ us, const int* __restrict__ ts,
          const float* __restrict__ b_t, unsigned short* __restrict__ hpred) {
    __shared__ uint4 tbl[19 * TBLP_STRIDE];                    // 39.2 KB
    __shared__ alignas(16) unsigned short htile[2][32][264];   // 33.8 KB double buffer
    __shared__ int act_l[32][KH];                              // 2.6 KB

    int tid = threadIdx.x, wave = tid >> 6, lane = tid & 63;
    int l15 = lane & 15, grp = lane >> 4, lk8 = grp << 3, r4 = grp << 2;
    int rb = blockIdx.x * 24;
    int u0 = us[0], u1 = us[1];
    int kmax = u0 > u1 ? u0 : u1;
    int j0 = wave * 32 + 2 * l15;    // lane owns cols (j0, j0+1)
    int jp = wave * 16 + l15;        // pair index in tbl

    // stage packed table + actions
    for (int i = tid; i < 19 * TBLP_STRIDE; i += 512) tbl[i] = tblpg[i];
    if (tid < 32 * KH) {
        int r = tid / KH, k2 = tid - r * KH;
        act_l[r][k2] = (r < 24) ? actg[(rb + r) * KH + k2] : AA;
    }

    // weights -> registers: ct = gate*2 + p; weight row = gate*256 + j0 + p
    bf16x8 wr[6][8];   // 192 VGPR
#pragma unroll
    for (int ct = 0; ct < 6; ++ct) {
        int wrow = (ct >> 1) * 256 + j0 + (ct & 1);
        const unsigned short* base = &whh_s[(size_t)wrow * HH];
#pragma unroll
        for (int kk = 0; kk < 8; ++kk)
            wr[ct][kk] = *reinterpret_cast<const bf16x8*>(&base[kk * 32 + lk8]);
    }
    float bhn0 = SCL_N * bhh[512 + j0];
    float bhn1 = SCL_N * bhh[512 + j0 + 1];

    // packed bf16 h master: hmp[rt][reg] = (h[row][j0], h[row][j0+1]), row = rt*16+r4+reg
    unsigned hmp[2][4];
#pragma unroll
    for (int rt = 0; rt < 2; ++rt)
#pragma unroll
        for (int reg = 0; reg < 4; ++reg) {
            int rowl = rt * 16 + r4 + reg;
            unsigned hv = 0u;
            if (rowl < 24) {
                int b = rb + rowl;
                int n = b / SS, s = b - n * SS;
                const float* src = &b_t[(size_t)(n * TT + ts[s]) * HH + j0];
                hv = (unsigned)f2b(src[0]) | ((unsigned)f2b(src[1]) << 16);
            }
            hmp[rt][reg] = hv;
        }

    // htile init: buf0 real rows = bf16(h0); pad rows and buf1 = 0
    for (int i = tid; i < 2 * 32 * 32; i += 512) {
        int buf = i >> 10, rem = i & 1023, row = rem >> 5, c8 = (rem & 31) << 3;
        uint4 pk = {0u, 0u, 0u, 0u};
        if (buf == 0 && row < 24) {
            int b = rb + row;
            int n = b / SS, s = b - n * SS;
            const float* src = &b_t[(size_t)(n * TT + ts[s]) * HH + c8];
            pk.x = f2b(src[0]) | ((unsigned)f2b(src[1]) << 16);
            pk.y = f2b(src[2]) | ((unsigned)f2b(src[3]) << 16);
            pk.z = f2b(src[4]) | ((unsigned)f2b(src[5]) << 16);
            pk.w = f2b(src[6]) | ((unsigned)f2b(src[7]) << 16);
        }
        *reinterpret_cast<uint4*>(&htile[buf][row][c8]) = pk;
    }
    __syncthreads();

    int cur = 0;
    for (int ki = 0; ki <= kmax; ++ki) {
        int nxt = cur ^ 1;
#pragma unroll
        for (int rt = 0; rt < 2; ++rt) {
            f32x4 aR[2] = {}, aZ[2] = {}, aN[2] = {};
#pragma unroll
            for (int kk = 0; kk < 8; ++kk) {
                bf16x8 ah = *reinterpret_cast<const bf16x8*>(&htile[cur][rt * 16 + l15][kk * 32 + lk8]);
                aR[0] = mfma16(ah, wr[0][kk], aR[0]);
                aR[1] = mfma16(ah, wr[1][kk], aR[1]);
                aZ[0] = mfma16(ah, wr[2][kk], aZ[0]);
                aZ[1] = mfma16(ah, wr[3][kk], aZ[1]);
                aN[0] = mfma16(ah, wr[4][kk], aN[0]);
                aN[1] = mfma16(ah, wr[5][kk], aN[1]);
            }
#pragma unroll
            for (int reg = 0; reg < 4; ++reg) {
                int rowl = rt * 16 + r4 + reg;
                uint4 gi = tbl[act_l[rowl][ki] * TBLP_STRIDE + jp];   // one b128: r,z,n pairs
                float r0 = rcp_f(1.f + exp2_f(aR[0][reg] + blo(gi.x)));
                float r1 = rcp_f(1.f + exp2_f(aR[1][reg] + bhi(gi.x)));
                float z0 = rcp_f(1.f + exp2_f(aZ[0][reg] + blo(gi.y)));
                float z1 = rcp_f(1.f + exp2_f(aZ[1][reg] + bhi(gi.y)));
                float tv0 = blo(gi.z) + r0 * (aN[0][reg] + bhn0);
                float tv1 = bhi(gi.z) + r1 * (aN[1][reg] + bhn1);
                float nv0 = 2.f * rcp_f(1.f + exp2_f(tv0)) - 1.f;
                float nv1 = 2.f * rcp_f(1.f + exp2_f(tv1)) - 1.f;
                unsigned hp = hmp[rt][reg];
                float hn0 = nv0 + z0 * (blo(hp) - nv0);
                float hn1 = nv1 + z1 * (bhi(hp) - nv1);
                unsigned hv = (unsigned)f2b(hn0) | ((unsigned)f2b(hn1) << 16);
                hmp[rt][reg] = hv;
                if (rowl < 24) {
                    *reinterpret_cast<unsigned*>(&htile[nxt][rowl][j0]) = hv;
                    if (ki == u0)
                        *reinterpret_cast<unsigned*>(&hpred[(size_t)(rb + rowl) * HH + j0]) = hv;
                    if (ki == u1)
                        *reinterpret_cast<unsigned*>(&hpred[(size_t)(BB + rb + rowl) * HH + j0]) = hv;
                }
            }
        }
        __syncthreads();   // nxt fully written; cur fully read (single barrier is safe)
        cur = nxt;
    }
}

// Fused 3-layer MLP + loss: 256 blocks x 48 rows. pred never leaves registers.
__device__ __forceinline__ int xsw(int row, int chunk) {
    return (row << 9) + ((chunk ^ (row & 7)) << 3);   // ushort index, 16B granules
}

__global__ void __launch_bounds__(512, 4)
k_mlp_loss(const unsigned short* __restrict__ hpred, const unsigned short* __restrict__ w1t,
           const unsigned short* __restrict__ w2t, const unsigned short* __restrict__ w3t,
           const float* __restrict__ b1, const float* __restrict__ b2,
           const float* __restrict__ b3, const float* __restrict__ z_t,
           const float* __restrict__ dones, const int* __restrict__ ts,
           const int* __restrict__ us, float* __restrict__ part) {
    __shared__ unsigned short xs[48 * 512];   // 49.2 KB
    __shared__ unsigned short zs[48 * 256];   // 24.6 KB (bf16 targets)
    __shared__ float rstat[48][8][3];         // 4.6 KB
    __shared__ float vmask[48];

    int tid = threadIdx.x, wave = tid >> 6, lane = tid & 63;
    int l15 = lane & 15, grp = lane >> 4, lk8 = grp << 3, r4 = grp << 2;
    int rb = blockIdx.x * 48;

    // per-row validity mask
    if (tid < 48) {
        int rg = rb + tid;
        int f = rg >= BB ? 1 : 0;
        int b = rg - f * BB;
        int n = b / SS, s = b - n * SS;
        int t = ts[s], u = us[f];
        float m = (t + u < TT - 1) ? 1.f : 0.f;
        if (m > 0.f) for (int jj = 0; jj <= u; ++jj) m *= (1.f - dones[n * TT + t + jj]);
        vmask[tid] = (m > 0.f) ? 1.f : 0.f;
    }
    // stage z targets -> bf16 LDS
    for (int i = tid; i < 48 * 64; i += 512) {
        int row = i >> 6, c4 = (i & 63) << 2;
        int rg = rb + row;
        int f = rg >= BB ? 1 : 0;
        int b = rg - f * BB;
        int n = b / SS, s = b - n * SS;
        int t = ts[s], u = us[f];
        uint2 pk = {0u, 0u};
        if (t + u < TT - 1) {
            float4 v = *reinterpret_cast<const float4*>(&z_t[(size_t)(n * TT + 1 + t + u) * HH + c4]);
            pk.x = f2b(v.x) | ((unsigned)f2b(v.y) << 16);
            pk.y = f2b(v.z) | ((unsigned)f2b(v.w) << 16);
        }
        *reinterpret_cast<uint2*>(&zs[row * 256 + c4]) = pk;
    }

    // Layer 1: x1 = relu(hpred @ W1 + b1), K=256
    {
        f32x4 acc[3][4] = {};
        for (int kk = 0; kk < 8; ++kk) {
            int k0 = kk * 32 + lk8;
            bf16x8 av[3];
#pragma unroll
            for (int rt = 0; rt < 3; ++rt)
                av[rt] = *reinterpret_cast<const bf16x8*>(&hpred[(size_t)(rb + rt * 16 + l15) * HH + k0]);
#pragma unroll
            for (int ct = 0; ct < 4; ++ct) {
                int col = wave * 64 + ct * 16 + l15;
                bf16x8 bv = *reinterpret_cast<const bf16x8*>(&w1t[(size_t)col * HH + k0]);
#pragma unroll
                for (int rt = 0; rt < 3; ++rt) acc[rt][ct] = mfma16(av[rt], bv, acc[rt][ct]);
            }
        }
#pragma unroll
        for (int ct = 0; ct < 4; ++ct) {
            int col = wave * 64 + ct * 16 + l15;
            float bb = b1[col];
#pragma unroll
            for (int rt = 0; rt < 3; ++rt)
#pragma unroll
                for (int reg = 0; reg < 4; ++reg)
                    xs[xsw(rt * 16 + r4 + reg, col >> 3) + (col & 7)] =
                        f2b(fmaxf(acc[rt][ct][reg] + bb, 0.f));
        }
    }
    __syncthreads();   // also covers zs/vmask staging

    // Layer 2: x2 = relu(x1 @ W2 + b2), K=512
    {
        f32x4 acc[3][4] = {};
        for (int kk = 0; kk < 16; ++kk) {
            bf16x8 av[3];
#pragma unroll
            for (int rt = 0; rt < 3; ++rt)
                av[rt] = *reinterpret_cast<const bf16x8*>(&xs[xsw(rt * 16 + l15, kk * 4 + grp)]);
#pragma unroll
            for (int ct = 0; ct < 4; ++ct) {
                int col = wave * 64 + ct * 16 + l15;
                bf16x8 bv = *reinterpret_cast<const bf16x8*>(&w2t[(size_t)col * MM + kk * 32 + lk8]);
#pragma unroll
                for (int rt = 0; rt < 3; ++rt) acc[rt][ct] = mfma16(av[rt], bv, acc[rt][ct]);
            }
        }
        __syncthreads();
#pragma unroll
        for (int ct = 0; ct < 4; ++ct) {
            int col = wave * 64 + ct * 16 + l15;
            float bb = b2[col];
#pragma unroll
            for (int rt = 0; rt < 3; ++rt)
#pragma unroll
                for (int reg = 0; reg < 4; ++reg)
                    xs[xsw(rt * 16 + r4 + reg, col >> 3) + (col & 7)] =
                        f2b(fmaxf(acc[rt][ct][reg] + bb, 0.f));
        }
    }
    __syncthreads();

    // Layer 3 + loss stats: wave owns 32 cols
    {
        f32x4 acc[3][2] = {};
        for (int kk = 0; kk < 16; ++kk) {
            bf16x8 av[3];
#pragma unroll
            for (int rt = 0; rt < 3; ++rt)
                av[rt] = *reinterpret_cast<const bf16x8*>(&xs[xsw(rt * 16 + l15, kk * 4 + grp)]);
#pragma unroll
            for (int ct = 0; ct < 2; ++ct) {
                int col = wave * 32 + ct * 16 + l15;
                bf16x8 bv = *reinterpret_cast<const bf16x8*>(&w3t[(size_t)col * MM + kk * 32 + lk8]);
#pragma unroll
                for (int rt = 0; rt < 3; ++rt) acc[rt][ct] = mfma16(av[rt], bv, acc[rt][ct]);
            }
        }
        float b3c0 = b3[wave * 32 + l15];
        float b3c1 = b3[wave * 32 + 16 + l15];
#pragma unroll
        for (int rt = 0; rt < 3; ++rt)
#pragma unroll
            for (int reg = 0; reg < 4; ++reg) {
                int row = rt * 16 + r4 + reg;
                float p0 = acc[rt][0][reg] + b3c0;
                float p1 = acc[rt][1][reg] + b3c1;
                float z0 = b2f(zs[row * 256 + wave * 32 + l15]);
                float z1 = b2f(zs[row * 256 + wave * 32 + 16 + l15]);
                float psq = p0 * p0 + p1 * p1;
                float zsq = z0 * z0 + z1 * z1;
                float pz  = p0 * z0 + p1 * z1;
#pragma unroll
                for (int o = 1; o < 16; o <<= 1) {
                    psq += __shfl_xor(psq, o);
                    zsq += __shfl_xor(zsq, o);
                    pz  += __shfl_xor(pz, o);
                }
                if (l15 == 0) {
                    rstat[row][wave][0] = psq;
                    rstat[row][wave][1] = zsq;
                    rstat[row][wave][2] = pz;
                }
            }
    }
    __syncthreads();

    // final per-row loss + block reduce (wave 0 only)
    if (tid < 64) {
        float a0 = 0.f, a1 = 0.f, a2 = 0.f;
        if (tid < 48) {
            float sp = 0.f, sz = 0.f, spz = 0.f;
#pragma unroll
            for (int w = 0; w < 8; ++w) {
                sp  += rstat[tid][w][0];
                sz  += rstat[tid][w][1];
                spz += rstat[tid][w][2];
            }
            float npn = sqrtf(sp), nzn = sqrtf(sz);
            float d = npn - 1.f;
            a2 = 0.02f * d * d;
            float mp = fmaxf(npn, 1e-8f), mz = fmaxf(nzn, 1e-8f);
            float lossr = (sp / (mp * mp) + sz / (mz * mz) - 2.f * spz / (mp * mz)) * (1.f / HH);
            float vm = vmask[tid];
            a0 = vm * lossr;
            a1 = vm;
        }
#pragma unroll
        for (int o = 1; o < 64; o <<= 1) {
            a0 += __shfl_xor(a0, o);
            a1 += __shfl_xor(a1, o);
            a2 += __shfl_xor(a2, o);
        }
        if (tid == 0) {
            part[blockIdx.x * 3 + 0] = a0;
            part[blockIdx.x * 3 + 1] = a1;
            part[blockIdx.x * 3 + 2] = a2;
        }
    }
}

// Final reduction over 256 partials.
__global__ void k_final(const float* __restrict__ part, float* out) {
    int tid = threadIdx.x, wave = tid >> 6, lane = tid & 63;
    float s0 = part[tid * 3 + 0];
    float s1 = part[tid * 3 + 1];
    float s2 = part[tid * 3 + 2];
    for (int o = 32; o; o >>= 1) {
        s0 += __shfl_xor(s0, o);
        s1 += __shfl_xor(s1, o);
        s2 += __shfl_xor(s2, o);
    }
    __shared__ float sm[4][3];
    if (lane == 0) { sm[wave][0] = s0; sm[wave][1] = s1; sm[wave][2] = s2; }
    __syncthreads();
    if (tid == 0) {
        float a = 0.f, b = 0.f, c = 0.f;
        for (int w = 0; w < 4; ++w) { a += sm[w][0]; b += sm[w][1]; c += sm[w][2]; }
        out[0] = a / fmaxf(b, 1.f) + c * (1.f / RR);
    }
}

extern "C" void kernel_launch(void* const* d_in, const int* in_sizes, int n_in,
                              void* d_out, int out_size, void* d_ws, size_t ws_size,
                              hipStream_t stream) {
    const int*   actions = (const int*)d_in[0];
    const float* dones   = (const float*)d_in[1];
    const float* b_t     = (const float*)d_in[2];
    const float* z_t     = (const float*)d_in[3];
    const int*   ts      = (const int*)d_in[4];
    const int*   us      = (const int*)d_in[5];
    const float* W_ih    = (const float*)d_in[6];
    const float* W_hh    = (const float*)d_in[7];
    const float* b_ih    = (const float*)d_in[8];
    const float* b_hh    = (const float*)d_in[9];
    const float* W1      = (const float*)d_in[10];
    const float* b1      = (const float*)d_in[11];
    const float* W2      = (const float*)d_in[12];
    const float* b2      = (const float*)d_in[13];
    const float* W3      = (const float*)d_in[14];
    const float* b3      = (const float*)d_in[15];

    char* ws = (char*)d_ws;
    int*            act   = (int*)(ws + OFF_ACT);
    unsigned short* hpred = (unsigned short*)(ws + OFF_HPRED);
    unsigned short* whh_s = (unsigned short*)(ws + OFF_WHH);
    unsigned short* w1t   = (unsigned short*)(ws + OFF_W1T);
    unsigned short* w2t   = (unsigned short*)(ws + OFF_W2T);
    unsigned short* w3t   = (unsigned short*)(ws + OFF_W3T);
    uint4*          tblp  = (uint4*)(ws + OFF_TBL);
    float*          part  = (float*)(ws + OFF_PART);

    // total prep elements: 196608+131072+262144+131072+2451+122880 = 846227 -> 3306 blocks
    k_prep<<<3306, 256, 0, stream>>>(W_hh, W1, W2, W3, W_ih, b_ih, b_hh, actions, ts,
                                     whh_s, w1t, w2t, w3t, tblp, act);
    k_gru_all<<<256, 512, 0, stream>>>(whh_s, tblp, b_hh, act, us, ts, b_t, hpred);
    k_mlp_loss<<<256, 512, 0, stream>>>(hpred, w1t, w2t, w3t, b1, b2, b3,
                                        z_t, dones, ts, us, part);
    k_final<<<1, 256, 0, stream>>>(part, (float*)d_out);
}

// Round 11
// 95.979 us; speedup vs baseline: 1.6157x; 1.2126x over previous
//
#include <hip/hip_runtime.h>
#include <hip/hip_bf16.h>
#include <math.h>

// Problem constants (from setup_inputs):
#define NN 1024
#define TT 128
#define SS 6
#define FF 2
#define HH 256
#define AA 18
#define MM 512
#define KH 20
#define BB (NN*SS)        // 6144
#define RR (FF*BB)        // 12288

#define SCL_RZ (-1.44269504089f)      // -log2(e): sigmoid(x)=rcp(1+exp2(-x*log2e))
#define SCL_N  (-2.88539008178f)      // -2*log2(e): tanh(x)=2*rcp(1+exp2(-2x*log2e))-1
#define TBLP_STRIDE 129               // uint4 stride: +16B bank shift per action row

typedef __bf16 bf16x8 __attribute__((ext_vector_type(8)));
typedef float f32x4 __attribute__((ext_vector_type(4)));

__device__ __forceinline__ f32x4 mfma16(bf16x8 a, bf16x8 b, f32x4 c) {
    return __builtin_amdgcn_mfma_f32_16x16x32_bf16(a, b, c, 0, 0, 0);
}
__device__ __forceinline__ unsigned short f2b(float f) {
    return __builtin_bit_cast(unsigned short, __float2bfloat16(f));
}
__device__ __forceinline__ float b2f(unsigned short u) {
    return __builtin_bit_cast(float, (unsigned)u << 16);
}
__device__ __forceinline__ float blo(unsigned u) { return __builtin_bit_cast(float, u << 16); }
__device__ __forceinline__ float bhi(unsigned u) { return __builtin_bit_cast(float, u & 0xffff0000u); }
__device__ __forceinline__ float rcp_f(float x)  { return __builtin_amdgcn_rcpf(x); }
__device__ __forceinline__ float exp2_f(float x) { return __builtin_amdgcn_exp2f(x); }

// ---- ws layout (bytes) ----
#define OFF_ACT   0UL                 // BB*KH int = 491,520
#define OFF_WHH   491520UL            // 768*256 bf16 (pre-scaled) = 393,216
#define OFF_W1T   884736UL            // 512*256 bf16 = 262,144
#define OFF_W2T   1146880UL           // 512*512 bf16 = 524,288
#define OFF_W3T   1671168UL           // 256*512 bf16 = 262,144
#define OFF_TBL   1933312UL           // 19*129 uint4 = 39,216
#define OFF_PART  1972528UL           // 256*3 f32 = 3,072
#define OFF_CNT   1975600UL           // 1 uint

// ---- fused-kernel LDS overlay (byte offsets into smem[103872]) ----
// GRU phase:  tbl @0 (39216) | htile @39216 (33792) | act_l @73008 (2560)
// MLP phase:  xs  @0 (49152) | zs @49152 (24576) | rstat @73728 (4608) | vmask @78336 (192)
// persistent: snap @78528 (48 x 264 bf16 = 25344)   -> total 103,872
#define SM_HTILE 39216
#define SM_ACT   73008
#define SM_XS    0
#define SM_ZS    49152
#define SM_RSTAT 73728
#define SM_VMASK 78336
#define SM_SNAP  78528
#define SM_TOTAL 103872

// Prep: scaled bf16 W_hh, transposed MLP weights, packed gi pair-table, action table.
__global__ void k_prep(const float* __restrict__ Whh, const float* __restrict__ W1,
                       const float* __restrict__ W2, const float* __restrict__ W3,
                       const float* __restrict__ Wih, const float* __restrict__ bih,
                       const float* __restrict__ bhh,
                       const int* __restrict__ actions, const int* __restrict__ ts,
                       unsigned short* whh_s, unsigned short* w1t, unsigned short* w2t,
                       unsigned short* w3t, uint4* tblp, int* act, unsigned* cnt) {
    if (blockIdx.x == 0 && threadIdx.x == 0) *cnt = 0u;   // reset last-block counter each call
    int idx = blockIdx.x * 256 + threadIdx.x;
    if (idx < 196608) {   // W_hh, pre-scaled per gate
        int wrow = idx >> 8;
        float scl = (wrow < 512) ? SCL_RZ : SCL_N;
        whh_s[idx] = f2b(Whh[idx] * scl);
        return;
    }
    idx -= 196608;
    if (idx < 131072) { int m = idx >> 8, k = idx & 255; w1t[idx] = f2b(W1[k * MM + m]); return; }
    idx -= 131072;
    if (idx < 262144) { int m = idx >> 9, k = idx & 511; w2t[idx] = f2b(W2[k * MM + m]); return; }
    idx -= 262144;
    if (idx < 131072) { int c = idx >> 9, k = idx & 511; w3t[idx] = f2b(W3[k * HH + c]); return; }
    idx -= 131072;
    if (idx < 19 * TBLP_STRIDE) {   // tblp[a][jp]: packed bf16 {r0r1, z0z1, n0n1, 0}
        int a = idx / TBLP_STRIDE, jp = idx - a * TBLP_STRIDE;
        uint4 o = {0u, 0u, 0u, 0u};
        if (jp < 128) {
            int j0 = jp * 2, j1 = j0 + 1;
            float wr0 = (a < AA) ? Wih[j0 * AA + a] : 0.f;
            float wr1 = (a < AA) ? Wih[j1 * AA + a] : 0.f;
            float wz0 = (a < AA) ? Wih[(256 + j0) * AA + a] : 0.f;
            float wz1 = (a < AA) ? Wih[(256 + j1) * AA + a] : 0.f;
            float wn0 = (a < AA) ? Wih[(512 + j0) * AA + a] : 0.f;
            float wn1 = (a < AA) ? Wih[(512 + j1) * AA + a] : 0.f;
            float r0 = SCL_RZ * (wr0 + bih[j0] + bhh[j0]);
            float r1 = SCL_RZ * (wr1 + bih[j1] + bhh[j1]);
            float z0 = SCL_RZ * (wz0 + bih[256 + j0] + bhh[256 + j0]);
            float z1 = SCL_RZ * (wz1 + bih[256 + j1] + bhh[256 + j1]);
            float n0 = SCL_N * (wn0 + bih[512 + j0]);
            float n1 = SCL_N * (wn1 + bih[512 + j1]);
            o.x = (unsigned)f2b(r0) | ((unsigned)f2b(r1) << 16);
            o.y = (unsigned)f2b(z0) | ((unsigned)f2b(z1) << 16);
            o.z = (unsigned)f2b(n0) | ((unsigned)f2b(n1) << 16);
        }
        tblp[idx] = o;
        return;
    }
    idx -= 19 * TBLP_STRIDE;
    if (idx < BB * KH) {   // act[b][k]: action index, AA for padded steps
        int b = idx / KH, k = idx - b * KH;
        int n = b / SS, s = b - n * SS;
        int tt = ts[s] + k;
        act[idx] = (tt < TT - 1) ? actions[n * TT + tt] : AA;
    }
}

__device__ __forceinline__ int xsw(int row, int chunk) {
    return (row << 9) + ((chunk ^ (row & 7)) << 3);   // ushort index, 16B granules
}

// Fused GRU rollout + 3-layer MLP + loss: 256 blocks x 512 thr, block owns 24 rows.
// Rollout: W_hh register-resident, dbuf htile, 1 barrier/step; snapshots -> LDS (no
// global hpred). MLP: 48 rows (24 x 2 snapshots) from LDS, weights streamed from L2;
// loss via {sum p^2, z^2, p.z}; last block (atomic counter) reduces 256 partials.
__global__ void __launch_bounds__(512, 2)
k_fused(const unsigned short* __restrict__ whh_s, const uint4* __restrict__ tblpg,
        const float* __restrict__ bhh, const int* __restrict__ actg,
        const int* __restrict__ us, const int* __restrict__ ts,
        const float* __restrict__ b_t,
        const unsigned short* __restrict__ w1t, const unsigned short* __restrict__ w2t,
        const unsigned short* __restrict__ w3t, const float* __restrict__ b1,
        const float* __restrict__ b2, const float* __restrict__ b3,
        const float* __restrict__ z_t, const float* __restrict__ dones,
        float* __restrict__ part, unsigned* __restrict__ cnt, float* __restrict__ out) {
    __shared__ alignas(16) char smem[SM_TOTAL];
    __shared__ unsigned ord;
    uint4* tbl = (uint4*)smem;
    unsigned short (*htile)[32][264] = (unsigned short (*)[32][264])(smem + SM_HTILE);
    int (*act_l)[KH] = (int (*)[KH])(smem + SM_ACT);
    unsigned short* xs = (unsigned short*)(smem + SM_XS);
    unsigned short* zs = (unsigned short*)(smem + SM_ZS);
    float (*rstat)[8][3] = (float (*)[8][3])(smem + SM_RSTAT);
    float* vmask = (float*)(smem + SM_VMASK);
    unsigned short* snap = (unsigned short*)(smem + SM_SNAP);   // [48][264]

    int tid = threadIdx.x, wave = tid >> 6, lane = tid & 63;
    int l15 = lane & 15, grp = lane >> 4, lk8 = grp << 3, r4 = grp << 2;
    int rb = blockIdx.x * 24;
    int u0 = us[0], u1 = us[1];
    int kmax = u0 > u1 ? u0 : u1;
    int j0 = wave * 32 + 2 * l15;    // lane owns cols (j0, j0+1)
    int jp = wave * 16 + l15;        // pair index in tbl

    // ===== GRU phase =====
    for (int i = tid; i < 19 * TBLP_STRIDE; i += 512) tbl[i] = tblpg[i];
    for (int i = tid; i < 32 * KH; i += 512) {
        int r = i / KH, k2 = i - r * KH;
        act_l[r][k2] = (r < 24) ? actg[(rb + r) * KH + k2] : AA;
    }

    bf16x8 wr[6][8];   // weights register-resident: ct = gate*2 + parity
#pragma unroll
    for (int ct = 0; ct < 6; ++ct) {
        int wrow = (ct >> 1) * 256 + j0 + (ct & 1);
        const unsigned short* base = &whh_s[(size_t)wrow * HH];
#pragma unroll
        for (int kk = 0; kk < 8; ++kk)
            wr[ct][kk] = *reinterpret_cast<const bf16x8*>(&base[kk * 32 + lk8]);
    }
    float bhn0 = SCL_N * bhh[512 + j0];
    float bhn1 = SCL_N * bhh[512 + j0 + 1];

    unsigned hmp[2][4];   // packed bf16 h master
#pragma unroll
    for (int rt = 0; rt < 2; ++rt)
#pragma unroll
        for (int reg = 0; reg < 4; ++reg) {
            int rowl = rt * 16 + r4 + reg;
            unsigned hv = 0u;
            if (rowl < 24) {
                int b = rb + rowl;
                int n = b / SS, s = b - n * SS;
                const float* src = &b_t[(size_t)(n * TT + ts[s]) * HH + j0];
                hv = (unsigned)f2b(src[0]) | ((unsigned)f2b(src[1]) << 16);
            }
            hmp[rt][reg] = hv;
        }

    for (int i = tid; i < 2 * 32 * 32; i += 512) {   // htile init
        int buf = i >> 10, rem = i & 1023, row = rem >> 5, c8 = (rem & 31) << 3;
        uint4 pk = {0u, 0u, 0u, 0u};
        if (buf == 0 && row < 24) {
            int b = rb + row;
            int n = b / SS, s = b - n * SS;
            const float* src = &b_t[(size_t)(n * TT + ts[s]) * HH + c8];
            pk.x = f2b(src[0]) | ((unsigned)f2b(src[1]) << 16);
            pk.y = f2b(src[2]) | ((unsigned)f2b(src[3]) << 16);
            pk.z = f2b(src[4]) | ((unsigned)f2b(src[5]) << 16);
            pk.w = f2b(src[6]) | ((unsigned)f2b(src[7]) << 16);
        }
        *reinterpret_cast<uint4*>(&htile[buf][row][c8]) = pk;
    }
    __syncthreads();

    int cur = 0;
    for (int ki = 0; ki <= kmax; ++ki) {
        int nxt = cur ^ 1;
#pragma unroll
        for (int rt = 0; rt < 2; ++rt) {
            f32x4 aR[2] = {}, aZ[2] = {}, aN[2] = {};
#pragma unroll
            for (int kk = 0; kk < 8; ++kk) {
                bf16x8 ah = *reinterpret_cast<const bf16x8*>(&htile[cur][rt * 16 + l15][kk * 32 + lk8]);
                aR[0] = mfma16(ah, wr[0][kk], aR[0]);
                aR[1] = mfma16(ah, wr[1][kk], aR[1]);
                aZ[0] = mfma16(ah, wr[2][kk], aZ[0]);
                aZ[1] = mfma16(ah, wr[3][kk], aZ[1]);
                aN[0] = mfma16(ah, wr[4][kk], aN[0]);
                aN[1] = mfma16(ah, wr[5][kk], aN[1]);
            }
#pragma unroll
            for (int reg = 0; reg < 4; ++reg) {
                int rowl = rt * 16 + r4 + reg;
                uint4 gi = tbl[act_l[rowl][ki] * TBLP_STRIDE + jp];
                float r0 = rcp_f(1.f + exp2_f(aR[0][reg] + blo(gi.x)));
                float r1 = rcp_f(1.f + exp2_f(aR[1][reg] + bhi(gi.x)));
                float z0 = rcp_f(1.f + exp2_f(aZ[0][reg] + blo(gi.y)));
                float z1 = rcp_f(1.f + exp2_f(aZ[1][reg] + bhi(gi.y)));
                float tv0 = blo(gi.z) + r0 * (aN[0][reg] + bhn0);
                float tv1 = bhi(gi.z) + r1 * (aN[1][reg] + bhn1);
                float nv0 = 2.f * rcp_f(1.f + exp2_f(tv0)) - 1.f;
                float nv1 = 2.f * rcp_f(1.f + exp2_f(tv1)) - 1.f;
                unsigned hp = hmp[rt][reg];
                float hn0 = nv0 + z0 * (blo(hp) - nv0);
                float hn1 = nv1 + z1 * (bhi(hp) - nv1);
                unsigned hv = (unsigned)f2b(hn0) | ((unsigned)f2b(hn1) << 16);
                hmp[rt][reg] = hv;
                if (rowl < 24) {
                    *reinterpret_cast<unsigned*>(&htile[nxt][rowl][j0]) = hv;
                    if (ki == u0)
                        *reinterpret_cast<unsigned*>(&snap[rowl * 264 + j0]) = hv;
                    if (ki == u1)
                        *reinterpret_cast<unsigned*>(&snap[(24 + rowl) * 264 + j0]) = hv;
                }
            }
        }
        __syncthreads();
        cur = nxt;
    }
    // rollout done; tbl/htile/act_l dead -> overlay becomes xs/zs/rstat/vmask

    // ===== MLP + loss phase (rows: 0-23 = u0 snapshot, 24-47 = u1 snapshot) =====
    if (tid < 48) {   // validity mask
        int f = tid / 24, lr = tid - f * 24;
        int b = rb + lr;
        int n = b / SS, s = b - n * SS;
        int t = ts[s], u = us[f];
        float m = (t + u < TT - 1) ? 1.f : 0.f;
        if (m > 0.f) for (int jj = 0; jj <= u; ++jj) m *= (1.f - dones[n * TT + t + jj]);
        vmask[tid] = (m > 0.f) ? 1.f : 0.f;
    }
    for (int i = tid; i < 48 * 64; i += 512) {   // stage z targets
        int row = i >> 6, c4 = (i & 63) << 2;
        int f = row / 24, lr = row - f * 24;
        int b = rb + lr;
        int n = b / SS, s = b - n * SS;
        int t = ts[s], u = us[f];
        uint2 pk = {0u, 0u};
        if (t + u < TT - 1) {
            float4 v = *reinterpret_cast<const float4*>(&z_t[(size_t)(n * TT + 1 + t + u) * HH + c4]);
            pk.x = f2b(v.x) | ((unsigned)f2b(v.y) << 16);
            pk.y = f2b(v.z) | ((unsigned)f2b(v.w) << 16);
        }
        *reinterpret_cast<uint2*>(&zs[row * 256 + c4]) = pk;
    }

    // Layer 1: x1 = relu(snap @ W1 + b1), K=256
    {
        f32x4 acc[3][4] = {};
        for (int kk = 0; kk < 8; ++kk) {
            int k0 = kk * 32 + lk8;
            bf16x8 av[3];
#pragma unroll
            for (int rt = 0; rt < 3; ++rt)
                av[rt] = *reinterpret_cast<const bf16x8*>(&snap[(rt * 16 + l15) * 264 + k0]);
#pragma unroll
            for (int ct = 0; ct < 4; ++ct) {
                int col = wave * 64 + ct * 16 + l15;
                bf16x8 bv = *reinterpret_cast<const bf16x8*>(&w1t[(size_t)col * HH + k0]);
#pragma unroll
                for (int rt = 0; rt < 3; ++rt) acc[rt][ct] = mfma16(av[rt], bv, acc[rt][ct]);
            }
        }
#pragma unroll
        for (int ct = 0; ct < 4; ++ct) {
            int col = wave * 64 + ct * 16 + l15;
            float bb = b1[col];
#pragma unroll
            for (int rt = 0; rt < 3; ++rt)
#pragma unroll
                for (int reg = 0; reg < 4; ++reg)
                    xs[xsw(rt * 16 + r4 + reg, col >> 3) + (col & 7)] =
                        f2b(fmaxf(acc[rt][ct][reg] + bb, 0.f));
        }
    }
    __syncthreads();   // covers xs + zs + vmask

    // Layer 2: x2 = relu(x1 @ W2 + b2), K=512
    {
        f32x4 acc[3][4] = {};
        for (int kk = 0; kk < 16; ++kk) {
            bf16x8 av[3];
#pragma unroll
            for (int rt = 0; rt < 3; ++rt)
                av[rt] = *reinterpret_cast<const bf16x8*>(&xs[xsw(rt * 16 + l15, kk * 4 + grp)]);
#pragma unroll
            for (int ct = 0; ct < 4; ++ct) {
                int col = wave * 64 + ct * 16 + l15;
                bf16x8 bv = *reinterpret_cast<const bf16x8*>(&w2t[(size_t)col * MM + kk * 32 + lk8]);
#pragma unroll
                for (int rt = 0; rt < 3; ++rt) acc[rt][ct] = mfma16(av[rt], bv, acc[rt][ct]);
            }
        }
        __syncthreads();
#pragma unroll
        for (int ct = 0; ct < 4; ++ct) {
            int col = wave * 64 + ct * 16 + l15;
            float bb = b2[col];
#pragma unroll
            for (int rt = 0; rt < 3; ++rt)
#pragma unroll
                for (int reg = 0; reg < 4; ++reg)
                    xs[xsw(rt * 16 + r4 + reg, col >> 3) + (col & 7)] =
                        f2b(fmaxf(acc[rt][ct][reg] + bb, 0.f));
        }
    }
    __syncthreads();

    // Layer 3 + loss stats: wave owns 32 cols
    {
        f32x4 acc[3][2] = {};
        for (int kk = 0; kk < 16; ++kk) {
            bf16x8 av[3];
#pragma unroll
            for (int rt = 0; rt < 3; ++rt)
                av[rt] = *reinterpret_cast<const bf16x8*>(&xs[xsw(rt * 16 + l15, kk * 4 + grp)]);
#pragma unroll
            for (int ct = 0; ct < 2; ++ct) {
                int col = wave * 32 + ct * 16 + l15;
                bf16x8 bv = *reinterpret_cast<const bf16x8*>(&w3t[(size_t)col * MM + kk * 32 + lk8]);
#pragma unroll
                for (int rt = 0; rt < 3; ++rt) acc[rt][ct] = mfma16(av[rt], bv, acc[rt][ct]);
            }
        }
        float b3c0 = b3[wave * 32 + l15];
        float b3c1 = b3[wave * 32 + 16 + l15];
#pragma unroll
        for (int rt = 0; rt < 3; ++rt)
#pragma unroll
            for (int reg = 0; reg < 4; ++reg) {
                int row = rt * 16 + r4 + reg;
                float p0 = acc[rt][0][reg] + b3c0;
                float p1 = acc[rt][1][reg] + b3c1;
                float z0 = b2f(zs[row * 256 + wave * 32 + l15]);
                float z1 = b2f(zs[row * 256 + wave * 32 + 16 + l15]);
                float psq = p0 * p0 + p1 * p1;
                float zsq = z0 * z0 + z1 * z1;
                float pz  = p0 * z0 + p1 * z1;
#pragma unroll
                for (int o = 1; o < 16; o <<= 1) {
                    psq += __shfl_xor(psq, o);
                    zsq += __shfl_xor(zsq, o);
                    pz  += __shfl_xor(pz, o);
                }
                if (l15 == 0) {
                    rstat[row][wave][0] = psq;
                    rstat[row][wave][1] = zsq;
                    rstat[row][wave][2] = pz;
                }
            }
    }
    __syncthreads();

    // per-row loss + block partials (wave 0)
    if (tid < 64) {
        float a0 = 0.f, a1 = 0.f, a2 = 0.f;
        if (tid < 48) {
            float sp = 0.f, sz = 0.f, spz = 0.f;
#pragma unroll
            for (int w = 0; w < 8; ++w) {
                sp  += rstat[tid][w][0];
                sz  += rstat[tid][w][1];
                spz += rstat[tid][w][2];
            }
            float npn = sqrtf(sp), nzn = sqrtf(sz);
            float d = npn - 1.f;
            a2 = 0.02f * d * d;
            float mp = fmaxf(npn, 1e-8f), mz = fmaxf(nzn, 1e-8f);
            float lossr = (sp / (mp * mp) + sz / (mz * mz) - 2.f * spz / (mp * mz)) * (1.f / HH);
            float vm = vmask[tid];
            a0 = vm * lossr;
            a1 = vm;
        }
#pragma unroll
        for (int o = 1; o < 64; o <<= 1) {
            a0 += __shfl_xor(a0, o);
            a1 += __shfl_xor(a1, o);
            a2 += __shfl_xor(a2, o);
        }
        if (tid == 0) {
            part[blockIdx.x * 3 + 0] = a0;
            part[blockIdx.x * 3 + 1] = a1;
            part[blockIdx.x * 3 + 2] = a2;
            __threadfence();
            ord = atomicAdd(cnt, 1u);
        }
    }
    __syncthreads();

    // last arriving block reduces all 256 partials (deterministic result)
    if (ord == 255u && tid < 64) {
        __threadfence();
        float s0 = 0.f, s1 = 0.f, s2 = 0.f;
        for (int i = tid; i < 256; i += 64) {
            s0 += part[i * 3 + 0];
            s1 += part[i * 3 + 1];
            s2 += part[i * 3 + 2];
        }
#pragma unroll
        for (int o = 1; o < 64; o <<= 1) {
            s0 += __shfl_xor(s0, o);
            s1 += __shfl_xor(s1, o);
            s2 += __shfl_xor(s2, o);
        }
        if (tid == 0) out[0] = s0 / fmaxf(s1, 1.f) + s2 * (1.f / RR);
    }
}

extern "C" void kernel_launch(void* const* d_in, const int* in_sizes, int n_in,
                              void* d_out, int out_size, void* d_ws, size_t ws_size,
                              hipStream_t stream) {
    const int*   actions = (const int*)d_in[0];
    const float* dones   = (const float*)d_in[1];
    const float* b_t     = (const float*)d_in[2];
    const float* z_t     = (const float*)d_in[3];
    const int*   ts      = (const int*)d_in[4];
    const int*   us      = (const int*)d_in[5];
    const float* W_ih    = (const float*)d_in[6];
    const float* W_hh    = (const float*)d_in[7];
    const float* b_ih    = (const float*)d_in[8];
    const float* b_hh    = (const float*)d_in[9];
    const float* W1      = (const float*)d_in[10];
    const float* b1      = (const float*)d_in[11];
    const float* W2      = (const float*)d_in[12];
    const float* b2      = (const float*)d_in[13];
    const float* W3      = (const float*)d_in[14];
    const float* b3      = (const float*)d_in[15];

    char* ws = (char*)d_ws;
    int*            act   = (int*)(ws + OFF_ACT);
    unsigned short* whh_s = (unsigned short*)(ws + OFF_WHH);
    unsigned short* w1t   = (unsigned short*)(ws + OFF_W1T);
    unsigned short* w2t   = (unsigned short*)(ws + OFF_W2T);
    unsigned short* w3t   = (unsigned short*)(ws + OFF_W3T);
    uint4*          tblp  = (uint4*)(ws + OFF_TBL);
    float*          part  = (float*)(ws + OFF_PART);
    unsigned*       cnt   = (unsigned*)(ws + OFF_CNT);

    // total prep elements: 196608+131072+262144+131072+2451+122880 = 846227 -> 3306 blocks
    k_prep<<<3306, 256, 0, stream>>>(W_hh, W1, W2, W3, W_ih, b_ih, b_hh, actions, ts,
                                     whh_s, w1t, w2t, w3t, tblp, act, cnt);
    k_fused<<<256, 512, 0, stream>>>(whh_s, tblp, b_hh, act, us, ts, b_t,
                                     w1t, w2t, w3t, b1, b2, b3, z_t, dones,
                                     part, cnt, (float*)d_out);
}